// Round 1
// baseline (747.975 us; speedup 1.0000x reference)
//
#include <hip/hip_runtime.h>
#include <math.h>

#define S_LEN 2048
#define BATCH 2
#define EMB 768
#define NH 8
#define HD 96
#define NTOK (BATCH*S_LEN)
#define RSQRT_D 0.10206207261596575f   // 1/sqrt(96)

// ---------------------------------------------------------------------------
// Block reductions (blockDim = 256 = 4 waves of 64)
// ---------------------------------------------------------------------------
__device__ __forceinline__ float block_sum256(float v, float* red) {
    #pragma unroll
    for (int off = 32; off > 0; off >>= 1) v += __shfl_down(v, off);
    int lane = threadIdx.x & 63, w = threadIdx.x >> 6;
    __syncthreads();
    if (lane == 0) red[w] = v;
    __syncthreads();
    return red[0] + red[1] + red[2] + red[3];
}

__device__ __forceinline__ float block_max256(float v, float* red) {
    #pragma unroll
    for (int off = 32; off > 0; off >>= 1) v = fmaxf(v, __shfl_down(v, off));
    int lane = threadIdx.x & 63, w = threadIdx.x >> 6;
    __syncthreads();
    if (lane == 0) red[w] = v;
    __syncthreads();
    return fmaxf(fmaxf(red[0], red[1]), fmaxf(red[2], red[3]));
}

// ---------------------------------------------------------------------------
// Kernel 1: QKV projection.  X[4096,768] @ W[768,768] + b -> [B,H,S,D] layout
// grid (EMB/64, NTOK/64, 3), block (16,16)
// ---------------------------------------------------------------------------
__global__ __launch_bounds__(256) void qkv_gemm_kernel(
    const float* __restrict__ X,
    const float* __restrict__ Wq, const float* __restrict__ bq,
    const float* __restrict__ Wk, const float* __restrict__ bk,
    const float* __restrict__ Wv, const float* __restrict__ bv,
    float* __restrict__ qo, float* __restrict__ ko, float* __restrict__ vo)
{
    const float* W; const float* bias; float* out;
    if (blockIdx.z == 0)      { W = Wq; bias = bq; out = qo; }
    else if (blockIdx.z == 1) { W = Wk; bias = bk; out = ko; }
    else                      { W = Wv; bias = bv; out = vo; }

    __shared__ float As[16][68];   // [kk][row]  (transposed for float4 inner reads)
    __shared__ float Bs[16][64];   // [kk][col]

    const int tx = threadIdx.x, ty = threadIdx.y;
    const int tid = ty * 16 + tx;
    const int row0 = blockIdx.y * 64;
    const int col0 = blockIdx.x * 64;

    float acc[4][4] = {};

    for (int k0 = 0; k0 < EMB; k0 += 16) {
        {
            int r  = tid >> 2;          // 0..63
            int kq = tid & 3;           // 0..3
            float4 a4 = *(const float4*)(X + (size_t)(row0 + r) * EMB + k0 + kq * 4);
            As[kq*4+0][r] = a4.x; As[kq*4+1][r] = a4.y;
            As[kq*4+2][r] = a4.z; As[kq*4+3][r] = a4.w;
            int kk = tid >> 4;          // 0..15
            int cq = tid & 15;          // 0..15
            *(float4*)&Bs[kk][cq*4] = *(const float4*)(W + (size_t)(k0 + kk) * EMB + col0 + cq * 4);
        }
        __syncthreads();
        #pragma unroll
        for (int kk = 0; kk < 16; ++kk) {
            float4 a4 = *(const float4*)&As[kk][ty * 4];
            float4 b4 = *(const float4*)&Bs[kk][tx * 4];
            float av[4] = {a4.x, a4.y, a4.z, a4.w};
            float bw[4] = {b4.x, b4.y, b4.z, b4.w};
            #pragma unroll
            for (int i = 0; i < 4; ++i)
                #pragma unroll
                for (int j = 0; j < 4; ++j)
                    acc[i][j] += av[i] * bw[j];
        }
        __syncthreads();
    }

    #pragma unroll
    for (int i = 0; i < 4; ++i) {
        int t = row0 + ty * 4 + i;
        int b = t >> 11, s = t & (S_LEN - 1);
        #pragma unroll
        for (int j = 0; j < 4; ++j) {
            int o = col0 + tx * 4 + j;
            int h = o / HD, d = o % HD;
            out[(((size_t)(b * NH + h)) * S_LEN + s) * HD + d] = acc[i][j] + bias[o];
        }
    }
}

// ---------------------------------------------------------------------------
// Kernel 2: scores[b,h,q,k] = (Q.K)/sqrt(D) + dist/angle bias + mask
// grid (S/64, S/64, B*H), block (16,16).  Writes raw scores into probs region.
// ---------------------------------------------------------------------------
__global__ __launch_bounds__(256) void scores_kernel(
    const float* __restrict__ q, const float* __restrict__ k,
    const float* __restrict__ dist, const float* __restrict__ ang,
    const float* __restrict__ mask,
    const float* __restrict__ pdw, const float* __restrict__ pdb,
    const float* __restrict__ paw, const float* __restrict__ pab,
    float* __restrict__ sc)
{
    const int bh = blockIdx.z;
    const int b  = bh >> 3;
    const float* qb = q + (size_t)bh * S_LEN * HD;
    const float* kb = k + (size_t)bh * S_LEN * HD;

    __shared__ float Qs[16][68];   // [kk][qrow]
    __shared__ float Ks[16][68];   // [kk][kcol]

    const int tx = threadIdx.x, ty = threadIdx.y;
    const int tid = ty * 16 + tx;
    const int row0 = blockIdx.y * 64;
    const int col0 = blockIdx.x * 64;

    float acc[4][4] = {};

    for (int k0 = 0; k0 < HD; k0 += 16) {
        int r  = tid >> 2;
        int kq = tid & 3;
        float4 a4 = *(const float4*)(qb + (size_t)(row0 + r) * HD + k0 + kq * 4);
        Qs[kq*4+0][r] = a4.x; Qs[kq*4+1][r] = a4.y;
        Qs[kq*4+2][r] = a4.z; Qs[kq*4+3][r] = a4.w;
        float4 b4 = *(const float4*)(kb + (size_t)(col0 + r) * HD + k0 + kq * 4);
        Ks[kq*4+0][r] = b4.x; Ks[kq*4+1][r] = b4.y;
        Ks[kq*4+2][r] = b4.z; Ks[kq*4+3][r] = b4.w;
        __syncthreads();
        #pragma unroll
        for (int kk = 0; kk < 16; ++kk) {
            float4 a4r = *(const float4*)&Qs[kk][ty * 4];
            float4 b4r = *(const float4*)&Ks[kk][tx * 4];
            float av[4] = {a4r.x, a4r.y, a4r.z, a4r.w};
            float bw[4] = {b4r.x, b4r.y, b4r.z, b4r.w};
            #pragma unroll
            for (int i = 0; i < 4; ++i)
                #pragma unroll
                for (int j = 0; j < 4; ++j)
                    acc[i][j] += av[i] * bw[j];
        }
        __syncthreads();
    }

    const float dw = *pdw, db = *pdb, aw = *paw, ab = *pab;
    float4 m4 = *(const float4*)(mask + b * S_LEN + col0 + tx * 4);
    float madd[4] = {(1.f - m4.x) * -10000.f, (1.f - m4.y) * -10000.f,
                     (1.f - m4.z) * -10000.f, (1.f - m4.w) * -10000.f};

    #pragma unroll
    for (int i = 0; i < 4; ++i) {
        int qr = row0 + ty * 4 + i;
        size_t boff = ((size_t)b * S_LEN + qr) * S_LEN + col0 + tx * 4;
        float4 d4 = *(const float4*)(dist + boff);
        float4 g4 = *(const float4*)(ang + boff);
        float4 o;
        o.x = acc[i][0] * RSQRT_D + dw * d4.x + db + aw * g4.x + ab + madd[0];
        o.y = acc[i][1] * RSQRT_D + dw * d4.y + db + aw * g4.y + ab + madd[1];
        o.z = acc[i][2] * RSQRT_D + dw * d4.z + db + aw * g4.z + ab + madd[2];
        o.w = acc[i][3] * RSQRT_D + dw * d4.w + db + aw * g4.w + ab + madd[3];
        *(float4*)(sc + ((size_t)bh * S_LEN + qr) * S_LEN + col0 + tx * 4) = o;
    }
}

// ---------------------------------------------------------------------------
// Kernel 3: row softmax in place over last dim (2048). grid B*H*S, block 256.
// ---------------------------------------------------------------------------
__global__ __launch_bounds__(256) void softmax_kernel(float* __restrict__ sc)
{
    const int row = blockIdx.x;
    float4* p4 = (float4*)(sc + (size_t)row * S_LEN);
    const int tid = threadIdx.x;
    __shared__ float red[4];

    float4 v0 = p4[tid];
    float4 v1 = p4[tid + 256];
    float m = fmaxf(fmaxf(fmaxf(v0.x, v0.y), fmaxf(v0.z, v0.w)),
                    fmaxf(fmaxf(v1.x, v1.y), fmaxf(v1.z, v1.w)));
    m = block_max256(m, red);

    float e[8];
    e[0] = expf(v0.x - m); e[1] = expf(v0.y - m); e[2] = expf(v0.z - m); e[3] = expf(v0.w - m);
    e[4] = expf(v1.x - m); e[5] = expf(v1.y - m); e[6] = expf(v1.z - m); e[7] = expf(v1.w - m);
    float s = ((e[0] + e[1]) + (e[2] + e[3])) + ((e[4] + e[5]) + (e[6] + e[7]));
    s = block_sum256(s, red);

    float inv = 1.0f / s;
    v0.x = e[0] * inv; v0.y = e[1] * inv; v0.z = e[2] * inv; v0.w = e[3] * inv;
    v1.x = e[4] * inv; v1.y = e[5] * inv; v1.z = e[6] * inv; v1.w = e[7] * inv;
    p4[tid]       = v0;
    p4[tid + 256] = v1;
}

// ---------------------------------------------------------------------------
// Kernel 4: ctx[b,h,q,:] = probs[b,h,q,:] @ V[b,h,:,:]   (per (b,h): 2048x2048 @ 2048x96)
// grid (S/64, B*H), block (16,16). ctx written in [B,S,E] layout.
// ---------------------------------------------------------------------------
__global__ __launch_bounds__(256) void pv_kernel(
    const float* __restrict__ probs, const float* __restrict__ v, float* __restrict__ ctx)
{
    const int bh = blockIdx.y;
    const int b = bh >> 3, h = bh & 7;
    const float* pb = probs + (size_t)bh * S_LEN * S_LEN;
    const float* vb = v + (size_t)bh * S_LEN * HD;
    const int row0 = blockIdx.x * 64;
    const int tx = threadIdx.x, ty = threadIdx.y;
    const int tid = ty * 16 + tx;

    __shared__ float Ps[64][68];   // [kk][qrow] transposed
    __shared__ float Vs[64][96];   // [kk][d]

    float acc[4][6] = {};

    for (int kc = 0; kc < S_LEN; kc += 64) {
        #pragma unroll
        for (int w = 0; w < 4; ++w) {
            int idx = tid + 256 * w;        // 0..1023 over 64x16 float4 grid
            int r = idx >> 4, kq = idx & 15;
            float4 p4 = *(const float4*)(pb + (size_t)(row0 + r) * S_LEN + kc + kq * 4);
            Ps[kq*4+0][r] = p4.x; Ps[kq*4+1][r] = p4.y;
            Ps[kq*4+2][r] = p4.z; Ps[kq*4+3][r] = p4.w;
        }
        #pragma unroll
        for (int w = 0; w < 6; ++w) {
            int idx = tid + 256 * w;        // 0..1535 over 64x24 float4 grid
            int r = idx / 24, cq = idx % 24;
            *(float4*)&Vs[r][cq*4] = *(const float4*)(vb + (size_t)(kc + r) * HD + cq * 4);
        }
        __syncthreads();
        #pragma unroll 8
        for (int kk = 0; kk < 64; ++kk) {
            float4 pr = *(const float4*)&Ps[kk][ty * 4];
            float pv[4] = {pr.x, pr.y, pr.z, pr.w};
            float2 va = *(const float2*)&Vs[kk][tx * 6];
            float2 vb2 = *(const float2*)&Vs[kk][tx * 6 + 2];
            float2 vc = *(const float2*)&Vs[kk][tx * 6 + 4];
            float vv[6] = {va.x, va.y, vb2.x, vb2.y, vc.x, vc.y};
            #pragma unroll
            for (int i = 0; i < 4; ++i)
                #pragma unroll
                for (int j = 0; j < 6; ++j)
                    acc[i][j] += pv[i] * vv[j];
        }
        __syncthreads();
    }

    #pragma unroll
    for (int i = 0; i < 4; ++i) {
        int qr = row0 + ty * 4 + i;
        #pragma unroll
        for (int j = 0; j < 6; ++j) {
            ctx[(size_t)(b * S_LEN + qr) * EMB + h * HD + tx * 6 + j] = acc[i][j];
        }
    }
}

// ---------------------------------------------------------------------------
// Kernel 5: res = ctx @ Wo + bo + hs   -> written into d_out (LN runs in place)
// grid (EMB/64, NTOK/64), block (16,16)
// ---------------------------------------------------------------------------
__global__ __launch_bounds__(256) void out_gemm_kernel(
    const float* __restrict__ X, const float* __restrict__ W, const float* __restrict__ bias,
    const float* __restrict__ hs, float* __restrict__ res)
{
    __shared__ float As[16][68];
    __shared__ float Bs[16][64];

    const int tx = threadIdx.x, ty = threadIdx.y;
    const int tid = ty * 16 + tx;
    const int row0 = blockIdx.y * 64;
    const int col0 = blockIdx.x * 64;

    float acc[4][4] = {};

    for (int k0 = 0; k0 < EMB; k0 += 16) {
        {
            int r  = tid >> 2;
            int kq = tid & 3;
            float4 a4 = *(const float4*)(X + (size_t)(row0 + r) * EMB + k0 + kq * 4);
            As[kq*4+0][r] = a4.x; As[kq*4+1][r] = a4.y;
            As[kq*4+2][r] = a4.z; As[kq*4+3][r] = a4.w;
            int kk = tid >> 4;
            int cq = tid & 15;
            *(float4*)&Bs[kk][cq*4] = *(const float4*)(W + (size_t)(k0 + kk) * EMB + col0 + cq * 4);
        }
        __syncthreads();
        #pragma unroll
        for (int kk = 0; kk < 16; ++kk) {
            float4 a4 = *(const float4*)&As[kk][ty * 4];
            float4 b4 = *(const float4*)&Bs[kk][tx * 4];
            float av[4] = {a4.x, a4.y, a4.z, a4.w};
            float bw[4] = {b4.x, b4.y, b4.z, b4.w};
            #pragma unroll
            for (int i = 0; i < 4; ++i)
                #pragma unroll
                for (int j = 0; j < 4; ++j)
                    acc[i][j] += av[i] * bw[j];
        }
        __syncthreads();
    }

    #pragma unroll
    for (int i = 0; i < 4; ++i) {
        int t = row0 + ty * 4 + i;
        int o = col0 + tx * 4;
        float4 b4 = *(const float4*)(bias + o);
        float4 h4 = *(const float4*)(hs + (size_t)t * EMB + o);
        float4 r4;
        r4.x = acc[i][0] + b4.x + h4.x;
        r4.y = acc[i][1] + b4.y + h4.y;
        r4.z = acc[i][2] + b4.z + h4.z;
        r4.w = acc[i][3] + b4.w + h4.w;
        *(float4*)(res + (size_t)t * EMB + o) = r4;
    }
}

// ---------------------------------------------------------------------------
// Kernel 6: LayerNorm in place over last dim 768. grid NTOK, block 256.
// ---------------------------------------------------------------------------
__global__ __launch_bounds__(256) void ln_kernel(
    float* __restrict__ res, const float* __restrict__ gamma, const float* __restrict__ beta)
{
    const int t = blockIdx.x;
    float* row = res + (size_t)t * EMB;
    const int tid = threadIdx.x;
    __shared__ float red[4];

    float x0 = row[tid], x1 = row[tid + 256], x2 = row[tid + 512];
    float s = block_sum256(x0 + x1 + x2, red);
    float mu = s * (1.0f / (float)EMB);
    float d0 = x0 - mu, d1 = x1 - mu, d2 = x2 - mu;
    float sq = block_sum256(d0 * d0 + d1 * d1 + d2 * d2, red);
    float var = sq * (1.0f / (float)EMB);
    float scale = rsqrtf(var + 1e-5f);

    row[tid]       = d0 * scale * gamma[tid]       + beta[tid];
    row[tid + 256] = d1 * scale * gamma[tid + 256] + beta[tid + 256];
    row[tid + 512] = d2 * scale * gamma[tid + 512] + beta[tid + 512];
}

// ---------------------------------------------------------------------------
extern "C" void kernel_launch(void* const* d_in, const int* in_sizes, int n_in,
                              void* d_out, int out_size, void* d_ws, size_t ws_size,
                              hipStream_t stream)
{
    (void)in_sizes; (void)n_in; (void)out_size; (void)ws_size;

    const float* hs   = (const float*)d_in[0];
    const float* dist = (const float*)d_in[1];
    const float* ang  = (const float*)d_in[2];
    const float* mask = (const float*)d_in[3];
    const float* Wq = (const float*)d_in[4];  const float* bq = (const float*)d_in[5];
    const float* Wk = (const float*)d_in[6];  const float* bk = (const float*)d_in[7];
    const float* Wv = (const float*)d_in[8];  const float* bv = (const float*)d_in[9];
    const float* dw = (const float*)d_in[10]; const float* db = (const float*)d_in[11];
    const float* aw = (const float*)d_in[12]; const float* ab = (const float*)d_in[13];
    const float* Wo = (const float*)d_in[14]; const float* bo = (const float*)d_in[15];
    const float* gamma = (const float*)d_in[16]; const float* beta = (const float*)d_in[17];

    float* out   = (float*)d_out;                      // [B,S,E]
    float* probs = out + (size_t)NTOK * EMB;           // [B,H,S,S]

    float* qbuf = (float*)d_ws;                        // [B,H,S,D]
    float* kbuf = qbuf + (size_t)NTOK * EMB;
    float* vbuf = kbuf + (size_t)NTOK * EMB;
    float* ctx  = qbuf;                                // reuse q region after scores

    dim3 blk(16, 16);

    qkv_gemm_kernel<<<dim3(EMB / 64, NTOK / 64, 3), blk, 0, stream>>>(
        hs, Wq, bq, Wk, bk, Wv, bv, qbuf, kbuf, vbuf);

    scores_kernel<<<dim3(S_LEN / 64, S_LEN / 64, BATCH * NH), blk, 0, stream>>>(
        qbuf, kbuf, dist, ang, mask, dw, db, aw, ab, probs);

    softmax_kernel<<<dim3(BATCH * NH * S_LEN), dim3(256), 0, stream>>>(probs);

    pv_kernel<<<dim3(S_LEN / 64, BATCH * NH), blk, 0, stream>>>(probs, vbuf, ctx);

    out_gemm_kernel<<<dim3(EMB / 64, NTOK / 64), blk, 0, stream>>>(
        ctx, Wo, bo, hs, out);

    ln_kernel<<<dim3(NTOK), dim3(256), 0, stream>>>(out, gamma, beta);
}

// Round 2
// 590.776 us; speedup vs baseline: 1.2661x; 1.2661x over previous
//
#include <hip/hip_runtime.h>
#include <math.h>

#define S_LEN 2048
#define BATCH 2
#define EMB 768
#define NH 8
#define HD 96
#define NTOK (BATCH*S_LEN)
#define RSQRT_D 0.10206207261596575f   // 1/sqrt(96)

typedef unsigned short u16;
typedef __attribute__((ext_vector_type(8))) short bf16x8;
typedef __attribute__((ext_vector_type(4))) float f32x4;

#define MFMA16(a,b,c) __builtin_amdgcn_mfma_f32_16x16x32_bf16(a,b,c,0,0,0)

__device__ __forceinline__ u16 f2bf(float f){
    unsigned u = __float_as_uint(f);
    return (u16)((u + 0x7fffu + ((u>>16)&1u)) >> 16);
}

union U16x8 { u16 u[8]; float4 f4; };

// ---------------------------------------------------------------------------
// f32 -> bf16 elementwise convert (vectorized x4)
// ---------------------------------------------------------------------------
__global__ __launch_bounds__(256) void cvt_bf16_kernel(
    const float* __restrict__ src, u16* __restrict__ dst, int n4)
{
    int i = blockIdx.x * 256 + threadIdx.x;
    if (i < n4) {
        float4 v = ((const float4*)src)[i];
        union { u16 u[4]; uint2 v2; } o;
        o.u[0] = f2bf(v.x); o.u[1] = f2bf(v.y); o.u[2] = f2bf(v.z); o.u[3] = f2bf(v.w);
        *(uint2*)(dst + (size_t)i*4) = o.v2;
    }
}

// ---------------------------------------------------------------------------
// W[768][768] f32 -> Wt[n][k] bf16 (transpose + convert). grid (12,12), 256thr
// ---------------------------------------------------------------------------
__global__ __launch_bounds__(256) void transcvt_kernel(
    const float* __restrict__ W, u16* __restrict__ Wt)
{
    __shared__ float T[64][65];
    const int t = threadIdx.x;
    const int k0 = blockIdx.y * 64, n0 = blockIdx.x * 64;
    #pragma unroll
    for (int i = 0; i < 4; ++i) {
        int idx = t + 256*i;            // 1024 = 64 rows x 16 float4
        int r = idx >> 4, c4 = idx & 15;
        float4 v = *(const float4*)(W + (size_t)(k0 + r)*EMB + n0 + c4*4);
        T[r][c4*4+0] = v.x; T[r][c4*4+1] = v.y; T[r][c4*4+2] = v.z; T[r][c4*4+3] = v.w;
    }
    __syncthreads();
    #pragma unroll
    for (int i = 0; i < 2; ++i) {
        int idx = t + 256*i;            // 512 = 64 n-rows x 8 chunks
        int n = idx >> 3, c = idx & 7;
        U16x8 o;
        #pragma unroll
        for (int e = 0; e < 8; ++e) o.u[e] = f2bf(T[c*8+e][n]);
        *(float4*)(Wt + (size_t)(n0 + n)*EMB + k0 + c*8) = o.f4;
    }
}

// ---------------------------------------------------------------------------
// QKV projection MFMA: hsb[4096,768]bf16 @ Wt^T + b -> q/k/v bf16 [B,H,S,D]
// grid (12, 64, 3), block 256
// ---------------------------------------------------------------------------
__global__ __launch_bounds__(256) void qkv_mfma_kernel(
    const u16* __restrict__ hsb,
    const u16* __restrict__ WqT, const float* __restrict__ bq,
    const u16* __restrict__ WkT, const float* __restrict__ bk,
    const u16* __restrict__ WvT, const float* __restrict__ bv,
    u16* __restrict__ qo, u16* __restrict__ ko, u16* __restrict__ vo)
{
    const u16* Wt; const float* bias; u16* out;
    if (blockIdx.z == 0)      { Wt = WqT; bias = bq; out = qo; }
    else if (blockIdx.z == 1) { Wt = WkT; bias = bk; out = ko; }
    else                      { Wt = WvT; bias = bv; out = vo; }

    __shared__ __align__(16) u16 As[64*64];
    __shared__ __align__(16) u16 Bs[64*64];
    const int tid = threadIdx.x;
    const int w = tid >> 6, lane = tid & 63, lh = lane & 15, g = lane >> 4;
    const int wm = w >> 1, wn = w & 1;
    const int row0 = blockIdx.y * 64, col0 = blockIdx.x * 64;

    f32x4 acc[2][2];
    #pragma unroll
    for (int i = 0; i < 2; ++i)
        #pragma unroll
        for (int j = 0; j < 2; ++j) acc[i][j] = (f32x4){0.f,0.f,0.f,0.f};

    for (int k0 = 0; k0 < EMB; k0 += 64) {
        __syncthreads();
        #pragma unroll
        for (int i = 0; i < 2; ++i) {
            int idx = tid + 256*i;      // 512 chunks of 16B
            int r = idx >> 3, c = idx & 7;
            float4 a4 = *(const float4*)(hsb + (size_t)(row0 + r)*EMB + k0 + c*8);
            *(float4*)(As + ((size_t)r*8 + (c ^ (r & 7)))*8) = a4;
            float4 b4 = *(const float4*)(Wt + (size_t)(col0 + r)*EMB + k0 + c*8);
            *(float4*)(Bs + ((size_t)r*8 + (c ^ (r & 7)))*8) = b4;
        }
        __syncthreads();
        bf16x8 af[2][2], bfr[2][2];
        #pragma unroll
        for (int mt = 0; mt < 2; ++mt)
            #pragma unroll
            for (int kk = 0; kk < 2; ++kk) {
                int r = wm*32 + mt*16 + lh;
                af[mt][kk] = *(const bf16x8*)(As + ((size_t)r*8 + ((kk*4+g) ^ (lh & 7)))*8);
            }
        #pragma unroll
        for (int nt = 0; nt < 2; ++nt)
            #pragma unroll
            for (int kk = 0; kk < 2; ++kk) {
                int r = wn*32 + nt*16 + lh;
                bfr[nt][kk] = *(const bf16x8*)(Bs + ((size_t)r*8 + ((kk*4+g) ^ (lh & 7)))*8);
            }
        #pragma unroll
        for (int mt = 0; mt < 2; ++mt)
            #pragma unroll
            for (int nt = 0; nt < 2; ++nt)
                #pragma unroll
                for (int kk = 0; kk < 2; ++kk)
                    acc[mt][nt] = MFMA16(af[mt][kk], bfr[nt][kk], acc[mt][nt]);
    }

    #pragma unroll
    for (int mt = 0; mt < 2; ++mt)
        #pragma unroll
        for (int nt = 0; nt < 2; ++nt)
            #pragma unroll
            for (int r = 0; r < 4; ++r) {
                int tt = row0 + wm*32 + mt*16 + g*4 + r;
                int o  = col0 + wn*32 + nt*16 + lh;
                float val = acc[mt][nt][r] + bias[o];
                int b = tt >> 11, s = tt & (S_LEN - 1);
                int h = o / HD, d = o - h*HD;
                out[((size_t)(b*NH + h)*S_LEN + s)*HD + d] = f2bf(val);
            }
}

// ---------------------------------------------------------------------------
// V transpose: vb[B,H,S,D] bf16 -> vt[B,H,D,S] bf16. grid (32,16), 256thr
// ---------------------------------------------------------------------------
__global__ __launch_bounds__(256) void vtrans_kernel(
    const u16* __restrict__ vb, u16* __restrict__ vt)
{
    const int bh = blockIdx.y;
    const int s0 = blockIdx.x * 64;
    __shared__ __align__(16) u16 T[64*96];
    const int t = threadIdx.x;
    #pragma unroll
    for (int i = 0; i < 3; ++i) {
        int idx = t + 256*i;            // 768 chunks: [s 64][c 12]
        int s = idx / 12, c = idx % 12;
        float4 v = *(const float4*)(vb + ((size_t)bh*S_LEN + s0 + s)*HD + c*8);
        *(float4*)(T + ((size_t)s*12 + c)*8) = v;
    }
    __syncthreads();
    #pragma unroll
    for (int i = 0; i < 3; ++i) {
        int idx = t + 256*i;            // 768 chunks: [d 96][c 8]
        int d = idx >> 3, c = idx & 7;
        U16x8 o;
        #pragma unroll
        for (int e = 0; e < 8; ++e) o.u[e] = T[(size_t)(c*8+e)*HD + d];
        *(float4*)(vt + ((size_t)bh*HD + d)*S_LEN + s0 + c*8) = o.f4;
    }
}

// ---------------------------------------------------------------------------
// Scores: raw s = QK^T/sqrt(D)+bias+mask -> sc (f32, probs region), plus
// online per-row max m and sum l (of exp(s-m)) -> mrow/lrow.
// grid (32 qtiles, 16 bh), block 256 (4 waves; wave w owns q-rows w*16..+15)
// ---------------------------------------------------------------------------
__global__ __launch_bounds__(256) void scores_mfma_kernel(
    const u16* __restrict__ qbf, const u16* __restrict__ kbf,
    const float* __restrict__ dist, const float* __restrict__ ang,
    const float* __restrict__ mask,
    const float* __restrict__ pdw, const float* __restrict__ pdb,
    const float* __restrict__ paw, const float* __restrict__ pab,
    float* __restrict__ sc, float* __restrict__ mrow, float* __restrict__ lrow)
{
    const int bh = blockIdx.y, b = bh >> 3;
    const int q0 = blockIdx.x * 64;
    const int tid = threadIdx.x;
    const int w = tid >> 6, lane = tid & 63, lh = lane & 15, g = lane >> 4;

    __shared__ __align__(16) u16 Qs[64*96];
    __shared__ __align__(16) u16 Ks[64*96];

    #pragma unroll
    for (int i = 0; i < 3; ++i) {
        int idx = tid + 256*i;          // 768 chunks: [r 64][c 12]
        int r = idx / 12, c = idx % 12;
        float4 v = *(const float4*)(qbf + ((size_t)bh*S_LEN + q0 + r)*HD + c*8);
        *(float4*)(Qs + ((size_t)r*12 + c)*8) = v;
    }
    __syncthreads();
    bf16x8 qf[3];
    #pragma unroll
    for (int kk = 0; kk < 3; ++kk)
        qf[kk] = *(const bf16x8*)(Qs + ((size_t)(w*16+lh)*12 + kk*4 + g)*8);

    const float DW = *pdw, AW = *paw;
    const float CB = *pdb + *pab;

    float m_run[4], l_run[4];
    #pragma unroll
    for (int r = 0; r < 4; ++r) { m_run[r] = -1e30f; l_run[r] = 0.f; }

    for (int kt = 0; kt < 32; ++kt) {
        __syncthreads();
        #pragma unroll
        for (int i = 0; i < 3; ++i) {
            int idx = tid + 256*i;
            int r = idx / 12, c = idx % 12;
            float4 v = *(const float4*)(kbf + ((size_t)bh*S_LEN + kt*64 + r)*HD + c*8);
            *(float4*)(Ks + ((size_t)r*12 + (c ^ (r & 3)))*8) = v;
        }
        __syncthreads();

        f32x4 acc[4];
        #pragma unroll
        for (int ct = 0; ct < 4; ++ct) acc[ct] = (f32x4){0.f,0.f,0.f,0.f};
        #pragma unroll
        for (int ct = 0; ct < 4; ++ct)
            #pragma unroll
            for (int kk = 0; kk < 3; ++kk) {
                bf16x8 kf = *(const bf16x8*)(Ks + ((size_t)(ct*16+lh)*12 + ((kk*4+g) ^ (lh & 3)))*8);
                acc[ct] = MFMA16(qf[kk], kf, acc[ct]);
            }

        #pragma unroll
        for (int ct = 0; ct < 4; ++ct) {
            int col = kt*64 + ct*16 + lh;
            float mv = mask[b*S_LEN + col];
            float madd = (1.f - mv) * -10000.f;
            #pragma unroll
            for (int r = 0; r < 4; ++r) {
                int qrow = q0 + w*16 + g*4 + r;
                size_t doff = ((size_t)b*S_LEN + qrow)*S_LEN + col;
                float s = acc[ct][r]*RSQRT_D + DW*dist[doff] + AW*ang[doff] + CB + madd;
                sc[((size_t)bh*S_LEN + qrow)*S_LEN + col] = s;
                acc[ct][r] = s;
            }
        }
        #pragma unroll
        for (int r = 0; r < 4; ++r) {
            float rmax = fmaxf(fmaxf(acc[0][r], acc[1][r]), fmaxf(acc[2][r], acc[3][r]));
            #pragma unroll
            for (int off = 8; off >= 1; off >>= 1) rmax = fmaxf(rmax, __shfl_xor(rmax, off));
            float mn = fmaxf(m_run[r], rmax);
            float es = expf(acc[0][r]-mn) + expf(acc[1][r]-mn)
                     + expf(acc[2][r]-mn) + expf(acc[3][r]-mn);
            #pragma unroll
            for (int off = 8; off >= 1; off >>= 1) es += __shfl_xor(es, off);
            l_run[r] = l_run[r]*expf(m_run[r]-mn) + es;
            m_run[r] = mn;
        }
    }
    if (lh == 0) {
        #pragma unroll
        for (int r = 0; r < 4; ++r) {
            int qrow = q0 + w*16 + g*4 + r;
            mrow[(bh << 11) + qrow] = m_run[r];
            lrow[(bh << 11) + qrow] = l_run[r];
        }
    }
}

// ---------------------------------------------------------------------------
// PV: p = exp(s-m)/l -> write probs (in place over raw sc, f32, d_out) ->
// bf16 -> MFMA with Vt -> ctx bf16 [B,S,E].  grid (32,16), block 256
// ---------------------------------------------------------------------------
__global__ __launch_bounds__(256) void pv_mfma_kernel(
    const float* __restrict__ sc, const float* __restrict__ mrow,
    const float* __restrict__ lrow, const u16* __restrict__ vt,
    float* __restrict__ probs, u16* __restrict__ ctxb)
{
    const int bh = blockIdx.y, b = bh >> 3, h = bh & 7;
    const int q0 = blockIdx.x * 64;
    const int tid = threadIdx.x;
    const int w = tid >> 6, lane = tid & 63, lh = lane & 15, g = lane >> 4;

    __shared__ __align__(16) u16 Ps[64*64];
    __shared__ __align__(16) u16 Vs[96*64];

    const int tr = tid >> 2, tc = tid & 3;
    const float mT   = mrow[(bh << 11) + q0 + tr];
    const float invl = 1.0f / lrow[(bh << 11) + q0 + tr];
    const float* srow = sc    + ((size_t)bh*S_LEN + q0 + tr)*S_LEN;
    float*       prow = probs + ((size_t)bh*S_LEN + q0 + tr)*S_LEN;

    f32x4 acc[6];
    #pragma unroll
    for (int ct = 0; ct < 6; ++ct) acc[ct] = (f32x4){0.f,0.f,0.f,0.f};

    for (int kt = 0; kt < 32; ++kt) {
        __syncthreads();
        // stage P: read raw scores, finish softmax, write probs, bf16 -> LDS
        U16x8 pk[2];
        #pragma unroll
        for (int j = 0; j < 4; ++j) {
            int col = kt*64 + tc*16 + j*4;
            float4 s4 = *(const float4*)(srow + col);
            float4 p;
            p.x = expf(s4.x - mT)*invl; p.y = expf(s4.y - mT)*invl;
            p.z = expf(s4.z - mT)*invl; p.w = expf(s4.w - mT)*invl;
            *(float4*)(prow + col) = p;
            int half = j >> 1, qo = (j & 1)*4;
            pk[half].u[qo+0] = f2bf(p.x); pk[half].u[qo+1] = f2bf(p.y);
            pk[half].u[qo+2] = f2bf(p.z); pk[half].u[qo+3] = f2bf(p.w);
        }
        int c0 = tc*2;
        *(float4*)(Ps + ((size_t)tr*8 + ( c0      ^ (tr & 7)))*8) = pk[0].f4;
        *(float4*)(Ps + ((size_t)tr*8 + ((c0 + 1) ^ (tr & 7)))*8) = pk[1].f4;
        // stage Vt tile [96 d][64 k]
        #pragma unroll
        for (int i = 0; i < 3; ++i) {
            int idx = tid + 256*i;      // 768 chunks
            int vr = idx >> 3, c = idx & 7;
            float4 v4 = *(const float4*)(vt + ((size_t)bh*HD + vr)*S_LEN + kt*64 + c*8);
            *(float4*)(Vs + ((size_t)vr*8 + (c ^ (vr & 7)))*8) = v4;
        }
        __syncthreads();

        bf16x8 pa[2];
        #pragma unroll
        for (int kk = 0; kk < 2; ++kk)
            pa[kk] = *(const bf16x8*)(Ps + ((size_t)(w*16+lh)*8 + ((kk*4+g) ^ (lh & 7)))*8);
        #pragma unroll
        for (int ct = 0; ct < 6; ++ct)
            #pragma unroll
            for (int kk = 0; kk < 2; ++kk) {
                bf16x8 vf = *(const bf16x8*)(Vs + ((size_t)(ct*16+lh)*8 + ((kk*4+g) ^ (lh & 7)))*8);
                acc[ct] = MFMA16(pa[kk], vf, acc[ct]);
            }
    }

    #pragma unroll
    for (int ct = 0; ct < 6; ++ct)
        #pragma unroll
        for (int r = 0; r < 4; ++r) {
            int qrow = q0 + w*16 + g*4 + r;
            ctxb[((size_t)(b*S_LEN + qrow))*EMB + h*HD + ct*16 + lh] = f2bf(acc[ct][r]);
        }
}

// ---------------------------------------------------------------------------
// Output proj MFMA: ctxb @ WoT^T + bo + hs -> res f32 (d_out). grid (12,64)
// ---------------------------------------------------------------------------
__global__ __launch_bounds__(256) void out_mfma_kernel(
    const u16* __restrict__ ctxb, const u16* __restrict__ WoT,
    const float* __restrict__ bo, const float* __restrict__ hs,
    float* __restrict__ res)
{
    __shared__ __align__(16) u16 As[64*64];
    __shared__ __align__(16) u16 Bs[64*64];
    const int tid = threadIdx.x;
    const int w = tid >> 6, lane = tid & 63, lh = lane & 15, g = lane >> 4;
    const int wm = w >> 1, wn = w & 1;
    const int row0 = blockIdx.y * 64, col0 = blockIdx.x * 64;

    f32x4 acc[2][2];
    #pragma unroll
    for (int i = 0; i < 2; ++i)
        #pragma unroll
        for (int j = 0; j < 2; ++j) acc[i][j] = (f32x4){0.f,0.f,0.f,0.f};

    for (int k0 = 0; k0 < EMB; k0 += 64) {
        __syncthreads();
        #pragma unroll
        for (int i = 0; i < 2; ++i) {
            int idx = tid + 256*i;
            int r = idx >> 3, c = idx & 7;
            float4 a4 = *(const float4*)(ctxb + (size_t)(row0 + r)*EMB + k0 + c*8);
            *(float4*)(As + ((size_t)r*8 + (c ^ (r & 7)))*8) = a4;
            float4 b4 = *(const float4*)(WoT + (size_t)(col0 + r)*EMB + k0 + c*8);
            *(float4*)(Bs + ((size_t)r*8 + (c ^ (r & 7)))*8) = b4;
        }
        __syncthreads();
        bf16x8 af[2][2], bfr[2][2];
        #pragma unroll
        for (int mt = 0; mt < 2; ++mt)
            #pragma unroll
            for (int kk = 0; kk < 2; ++kk) {
                int r = wm*32 + mt*16 + lh;
                af[mt][kk] = *(const bf16x8*)(As + ((size_t)r*8 + ((kk*4+g) ^ (lh & 7)))*8);
            }
        #pragma unroll
        for (int nt = 0; nt < 2; ++nt)
            #pragma unroll
            for (int kk = 0; kk < 2; ++kk) {
                int r = wn*32 + nt*16 + lh;
                bfr[nt][kk] = *(const bf16x8*)(Bs + ((size_t)r*8 + ((kk*4+g) ^ (lh & 7)))*8);
            }
        #pragma unroll
        for (int mt = 0; mt < 2; ++mt)
            #pragma unroll
            for (int nt = 0; nt < 2; ++nt)
                #pragma unroll
                for (int kk = 0; kk < 2; ++kk)
                    acc[mt][nt] = MFMA16(af[mt][kk], bfr[nt][kk], acc[mt][nt]);
    }

    #pragma unroll
    for (int mt = 0; mt < 2; ++mt)
        #pragma unroll
        for (int nt = 0; nt < 2; ++nt)
            #pragma unroll
            for (int r = 0; r < 4; ++r) {
                int tt = row0 + wm*32 + mt*16 + g*4 + r;
                int o  = col0 + wn*32 + nt*16 + lh;
                res[(size_t)tt*EMB + o] = acc[mt][nt][r] + bo[o] + hs[(size_t)tt*EMB + o];
            }
}

// ---------------------------------------------------------------------------
// LayerNorm in place over last dim 768. grid NTOK, block 256.
// ---------------------------------------------------------------------------
__device__ __forceinline__ float block_sum256(float v, float* red) {
    #pragma unroll
    for (int off = 32; off > 0; off >>= 1) v += __shfl_down(v, off);
    int lane = threadIdx.x & 63, w = threadIdx.x >> 6;
    __syncthreads();
    if (lane == 0) red[w] = v;
    __syncthreads();
    return red[0] + red[1] + red[2] + red[3];
}

__global__ __launch_bounds__(256) void ln_kernel(
    float* __restrict__ res, const float* __restrict__ gamma, const float* __restrict__ beta)
{
    const int t = blockIdx.x;
    float* row = res + (size_t)t * EMB;
    const int tid = threadIdx.x;
    __shared__ float red[4];

    float x0 = row[tid], x1 = row[tid + 256], x2 = row[tid + 512];
    float s = block_sum256(x0 + x1 + x2, red);
    float mu = s * (1.0f / (float)EMB);
    float d0 = x0 - mu, d1 = x1 - mu, d2 = x2 - mu;
    float sq = block_sum256(d0*d0 + d1*d1 + d2*d2, red);
    float var = sq * (1.0f / (float)EMB);
    float scale = rsqrtf(var + 1e-5f);

    row[tid]       = d0 * scale * gamma[tid]       + beta[tid];
    row[tid + 256] = d1 * scale * gamma[tid + 256] + beta[tid + 256];
    row[tid + 512] = d2 * scale * gamma[tid + 512] + beta[tid + 512];
}

// ---------------------------------------------------------------------------
extern "C" void kernel_launch(void* const* d_in, const int* in_sizes, int n_in,
                              void* d_out, int out_size, void* d_ws, size_t ws_size,
                              hipStream_t stream)
{
    (void)in_sizes; (void)n_in; (void)out_size; (void)ws_size;

    const float* hs   = (const float*)d_in[0];
    const float* dist = (const float*)d_in[1];
    const float* ang  = (const float*)d_in[2];
    const float* mask = (const float*)d_in[3];
    const float* Wq = (const float*)d_in[4];  const float* bq = (const float*)d_in[5];
    const float* Wk = (const float*)d_in[6];  const float* bk = (const float*)d_in[7];
    const float* Wv = (const float*)d_in[8];  const float* bv = (const float*)d_in[9];
    const float* dw = (const float*)d_in[10]; const float* db = (const float*)d_in[11];
    const float* aw = (const float*)d_in[12]; const float* ab = (const float*)d_in[13];
    const float* Wo = (const float*)d_in[14]; const float* bo = (const float*)d_in[15];
    const float* gamma = (const float*)d_in[16]; const float* beta = (const float*)d_in[17];

    float* out   = (float*)d_out;                      // [B,S,E]
    float* probs = out + (size_t)NTOK * EMB;           // [B,H,S,S]

    // workspace (bf16 buffers + row stats) — ~36.4 MB total
    u16* hsb = (u16*)d_ws;
    u16* WqT = hsb + (size_t)NTOK*EMB;
    u16* WkT = WqT + (size_t)EMB*EMB;
    u16* WvT = WkT + (size_t)EMB*EMB;
    u16* WoT = WvT + (size_t)EMB*EMB;
    u16* qb  = WoT + (size_t)EMB*EMB;
    u16* kb  = qb + (size_t)NTOK*EMB;
    u16* vb  = kb + (size_t)NTOK*EMB;
    u16* vtb = vb + (size_t)NTOK*EMB;
    u16* ctxb = qb;                                    // reuse q region after scores
    float* mrow = (float*)(vtb + (size_t)NTOK*EMB);
    float* lrow = mrow + (size_t)BATCH*NH*S_LEN;

    cvt_bf16_kernel<<<dim3(NTOK*EMB/4/256), dim3(256), 0, stream>>>(hs, hsb, NTOK*EMB/4);
    transcvt_kernel<<<dim3(12,12), dim3(256), 0, stream>>>(Wq, WqT);
    transcvt_kernel<<<dim3(12,12), dim3(256), 0, stream>>>(Wk, WkT);
    transcvt_kernel<<<dim3(12,12), dim3(256), 0, stream>>>(Wv, WvT);
    transcvt_kernel<<<dim3(12,12), dim3(256), 0, stream>>>(Wo, WoT);

    qkv_mfma_kernel<<<dim3(EMB/64, NTOK/64, 3), dim3(256), 0, stream>>>(
        hsb, WqT, bq, WkT, bk, WvT, bv, qb, kb, vb);

    vtrans_kernel<<<dim3(S_LEN/64, BATCH*NH), dim3(256), 0, stream>>>(vb, vtb);

    scores_mfma_kernel<<<dim3(S_LEN/64, BATCH*NH), dim3(256), 0, stream>>>(
        qb, kb, dist, ang, mask, dw, db, aw, ab, probs, mrow, lrow);

    pv_mfma_kernel<<<dim3(S_LEN/64, BATCH*NH), dim3(256), 0, stream>>>(
        probs, mrow, lrow, vtb, probs, ctxb);

    out_mfma_kernel<<<dim3(EMB/64, NTOK/64), dim3(256), 0, stream>>>(
        ctxb, WoT, bo, hs, out);

    ln_kernel<<<dim3(NTOK), dim3(256), 0, stream>>>(out, gamma, beta);
}

// Round 3
// 372.035 us; speedup vs baseline: 2.0105x; 1.5880x over previous
//
#include <hip/hip_runtime.h>
#include <math.h>

#define S_LEN 2048
#define BATCH 2
#define EMB 768
#define NH 8
#define HD 96
#define NTOK (BATCH*S_LEN)
#define RSQRT_D 0.10206207261596575f   // 1/sqrt(96)

typedef unsigned short u16;
typedef __attribute__((ext_vector_type(8))) short bf16x8;
typedef __attribute__((ext_vector_type(4))) float f32x4;

#define MFMA16(a,b,c) __builtin_amdgcn_mfma_f32_16x16x32_bf16(a,b,c,0,0,0)

__device__ __forceinline__ u16 f2bf(float f){
    unsigned u = __float_as_uint(f);
    return (u16)((u + 0x7fffu + ((u>>16)&1u)) >> 16);
}

union U16x8 { u16 u[8]; float4 f4; };
union U16x4 { u16 u[4]; uint2 v2; };

// ---------------------------------------------------------------------------
// f32 -> bf16 elementwise convert (vectorized x4)
// ---------------------------------------------------------------------------
__global__ __launch_bounds__(256) void cvt_bf16_kernel(
    const float* __restrict__ src, u16* __restrict__ dst, int n4)
{
    int i = blockIdx.x * 256 + threadIdx.x;
    if (i < n4) {
        float4 v = ((const float4*)src)[i];
        U16x4 o;
        o.u[0] = f2bf(v.x); o.u[1] = f2bf(v.y); o.u[2] = f2bf(v.z); o.u[3] = f2bf(v.w);
        *(uint2*)(dst + (size_t)i*4) = o.v2;
    }
}

// ---------------------------------------------------------------------------
// W[768][768] f32 -> Wt[n][k] bf16 (transpose + convert). grid (12,12), 256thr
// ---------------------------------------------------------------------------
__global__ __launch_bounds__(256) void transcvt_kernel(
    const float* __restrict__ W, u16* __restrict__ Wt)
{
    __shared__ float T[64][65];
    const int t = threadIdx.x;
    const int k0 = blockIdx.y * 64, n0 = blockIdx.x * 64;
    #pragma unroll
    for (int i = 0; i < 4; ++i) {
        int idx = t + 256*i;
        int r = idx >> 4, c4 = idx & 15;
        float4 v = *(const float4*)(W + (size_t)(k0 + r)*EMB + n0 + c4*4);
        T[r][c4*4+0] = v.x; T[r][c4*4+1] = v.y; T[r][c4*4+2] = v.z; T[r][c4*4+3] = v.w;
    }
    __syncthreads();
    #pragma unroll
    for (int i = 0; i < 2; ++i) {
        int idx = t + 256*i;
        int n = idx >> 3, c = idx & 7;
        U16x8 o;
        #pragma unroll
        for (int e = 0; e < 8; ++e) o.u[e] = f2bf(T[c*8+e][n]);
        *(float4*)(Wt + (size_t)(n0 + n)*EMB + k0 + c*8) = o.f4;
    }
}

// ---------------------------------------------------------------------------
// QKV projection MFMA (unchanged from round 2)
// ---------------------------------------------------------------------------
__global__ __launch_bounds__(256) void qkv_mfma_kernel(
    const u16* __restrict__ hsb,
    const u16* __restrict__ WqT, const float* __restrict__ bq,
    const u16* __restrict__ WkT, const float* __restrict__ bk,
    const u16* __restrict__ WvT, const float* __restrict__ bv,
    u16* __restrict__ qo, u16* __restrict__ ko, u16* __restrict__ vo)
{
    const u16* Wt; const float* bias; u16* out;
    if (blockIdx.z == 0)      { Wt = WqT; bias = bq; out = qo; }
    else if (blockIdx.z == 1) { Wt = WkT; bias = bk; out = ko; }
    else                      { Wt = WvT; bias = bv; out = vo; }

    __shared__ __align__(16) u16 As[64*64];
    __shared__ __align__(16) u16 Bs[64*64];
    const int tid = threadIdx.x;
    const int w = tid >> 6, lane = tid & 63, lh = lane & 15, g = lane >> 4;
    const int wm = w >> 1, wn = w & 1;
    const int row0 = blockIdx.y * 64, col0 = blockIdx.x * 64;

    f32x4 acc[2][2];
    #pragma unroll
    for (int i = 0; i < 2; ++i)
        #pragma unroll
        for (int j = 0; j < 2; ++j) acc[i][j] = (f32x4){0.f,0.f,0.f,0.f};

    for (int k0 = 0; k0 < EMB; k0 += 64) {
        __syncthreads();
        #pragma unroll
        for (int i = 0; i < 2; ++i) {
            int idx = tid + 256*i;
            int r = idx >> 3, c = idx & 7;
            float4 a4 = *(const float4*)(hsb + (size_t)(row0 + r)*EMB + k0 + c*8);
            *(float4*)(As + ((size_t)r*8 + (c ^ (r & 7)))*8) = a4;
            float4 b4 = *(const float4*)(Wt + (size_t)(col0 + r)*EMB + k0 + c*8);
            *(float4*)(Bs + ((size_t)r*8 + (c ^ (r & 7)))*8) = b4;
        }
        __syncthreads();
        bf16x8 af[2][2], bfr[2][2];
        #pragma unroll
        for (int mt = 0; mt < 2; ++mt)
            #pragma unroll
            for (int kk = 0; kk < 2; ++kk) {
                int r = wm*32 + mt*16 + lh;
                af[mt][kk] = *(const bf16x8*)(As + ((size_t)r*8 + ((kk*4+g) ^ (lh & 7)))*8);
            }
        #pragma unroll
        for (int nt = 0; nt < 2; ++nt)
            #pragma unroll
            for (int kk = 0; kk < 2; ++kk) {
                int r = wn*32 + nt*16 + lh;
                bfr[nt][kk] = *(const bf16x8*)(Bs + ((size_t)r*8 + ((kk*4+g) ^ (lh & 7)))*8);
            }
        #pragma unroll
        for (int mt = 0; mt < 2; ++mt)
            #pragma unroll
            for (int nt = 0; nt < 2; ++nt)
                #pragma unroll
                for (int kk = 0; kk < 2; ++kk)
                    acc[mt][nt] = MFMA16(af[mt][kk], bfr[nt][kk], acc[mt][nt]);
    }

    #pragma unroll
    for (int mt = 0; mt < 2; ++mt)
        #pragma unroll
        for (int nt = 0; nt < 2; ++nt)
            #pragma unroll
            for (int r = 0; r < 4; ++r) {
                int tt = row0 + wm*32 + mt*16 + g*4 + r;
                int o  = col0 + wn*32 + nt*16 + lh;
                float val = acc[mt][nt][r] + bias[o];
                int b = tt >> 11, s = tt & (S_LEN - 1);
                int h = o / HD, d = o - h*HD;
                out[((size_t)(b*NH + h)*S_LEN + s)*HD + d] = f2bf(val);
            }
}

// ---------------------------------------------------------------------------
// V transpose: vb[B,H,S,D] bf16 -> vt[B,H,D,S] bf16 (unchanged)
// ---------------------------------------------------------------------------
__global__ __launch_bounds__(256) void vtrans_kernel(
    const u16* __restrict__ vb, u16* __restrict__ vt)
{
    const int bh = blockIdx.y;
    const int s0 = blockIdx.x * 64;
    __shared__ __align__(16) u16 T[64*96];
    const int t = threadIdx.x;
    #pragma unroll
    for (int i = 0; i < 3; ++i) {
        int idx = t + 256*i;
        int s = idx / 12, c = idx % 12;
        float4 v = *(const float4*)(vb + ((size_t)bh*S_LEN + s0 + s)*HD + c*8);
        *(float4*)(T + ((size_t)s*12 + c)*8) = v;
    }
    __syncthreads();
    #pragma unroll
    for (int i = 0; i < 3; ++i) {
        int idx = t + 256*i;
        int d = idx >> 3, c = idx & 7;
        U16x8 o;
        #pragma unroll
        for (int e = 0; e < 8; ++e) o.u[e] = T[(size_t)(c*8+e)*HD + d];
        *(float4*)(vt + ((size_t)bh*HD + d)*S_LEN + s0 + c*8) = o.f4;
    }
}

// ---------------------------------------------------------------------------
// Pass 1 (scores): 32 q-rows/block, grid (64,16), block 256.
// Per kt (64 cols): stage K -> MFMA -> acc->LDS -> vectorized epilogue
// (float4 dist/ang/mask loads, float4 raw-score stores, online m/l in LDS).
// ---------------------------------------------------------------------------
__global__ __launch_bounds__(256) void scores_mfma_kernel(
    const u16* __restrict__ qbf, const u16* __restrict__ kbf,
    const float* __restrict__ dist, const float* __restrict__ ang,
    const float* __restrict__ mask,
    const float* __restrict__ pdw, const float* __restrict__ pdb,
    const float* __restrict__ paw, const float* __restrict__ pab,
    float* __restrict__ sc, float* __restrict__ mrow, float* __restrict__ lrow)
{
    const int bh = blockIdx.y, b = bh >> 3;
    const int q0 = blockIdx.x * 32;
    const int tid = threadIdx.x;
    const int lane = tid & 63, w = tid >> 6, lh = lane & 15, g = lane >> 4;
    const int wr = (w & 1) * 16;        // wave's q-row base within tile
    const int wc = (w >> 1) * 32;       // wave's col base within kt tile

    __shared__ __align__(16) u16 Qs[32*96];
    __shared__ __align__(16) u16 Ks[64*96];
    __shared__ __align__(16) float Sf[32*68];
    __shared__ float mL[32], lL[32];

    // stage Q tile (32 rows x 12 chunks), swizzle c ^= (r>>1)&3
    #pragma unroll
    for (int i = 0; i < 2; ++i) {
        int idx = tid + 256*i;
        if (idx < 384) {
            int r = idx / 12, c = idx % 12;
            float4 v = *(const float4*)(qbf + ((size_t)bh*S_LEN + q0 + r)*HD + c*8);
            *(float4*)(Qs + ((size_t)r*12 + (c ^ ((r >> 1) & 3)))*8) = v;
        }
    }
    if (tid < 32) { mL[tid] = -1e30f; lL[tid] = 0.f; }
    __syncthreads();

    bf16x8 qf[3];
    #pragma unroll
    for (int kk = 0; kk < 3; ++kk) {
        int r = wr + lh;
        qf[kk] = *(const bf16x8*)(Qs + ((size_t)r*12 + ((kk*4+g) ^ ((r >> 1) & 3)))*8);
    }

    const float DW = *pdw, AW = *paw, CB = *pdb + *pab;
    const int trow = tid >> 4;          // epilogue row (0..15), +16 for i=1
    const int c4   = tid & 15;          // epilogue float4 col chunk

    for (int kt = 0; kt < 32; ++kt) {
        // stage K tile (64 rows x 12 chunks)
        #pragma unroll
        for (int i = 0; i < 3; ++i) {
            int idx = tid + 256*i;
            int r = idx / 12, c = idx % 12;
            float4 v = *(const float4*)(kbf + ((size_t)bh*S_LEN + kt*64 + r)*HD + c*8);
            *(float4*)(Ks + ((size_t)r*12 + (c ^ ((r >> 1) & 3)))*8) = v;
        }
        __syncthreads();

        f32x4 acc[2];
        #pragma unroll
        for (int ct = 0; ct < 2; ++ct) acc[ct] = (f32x4){0.f,0.f,0.f,0.f};
        #pragma unroll
        for (int ct = 0; ct < 2; ++ct)
            #pragma unroll
            for (int kk = 0; kk < 3; ++kk) {
                int kr = wc + ct*16 + lh;
                bf16x8 kf = *(const bf16x8*)(Ks + ((size_t)kr*12 + ((kk*4+g) ^ ((kr >> 1) & 3)))*8);
                acc[ct] = MFMA16(qf[kk], kf, acc[ct]);
            }
        // accumulators -> LDS f32 tile
        #pragma unroll
        for (int ct = 0; ct < 2; ++ct)
            #pragma unroll
            for (int r = 0; r < 4; ++r)
                Sf[(wr + g*4 + r)*68 + wc + ct*16 + lh] = acc[ct][r];
        __syncthreads();

        // vectorized epilogue: 2 rows per thread, float4 per row
        float4 m4 = *(const float4*)(mask + b*S_LEN + kt*64 + c4*4);
        float ma0 = (1.f - m4.x) * -10000.f, ma1 = (1.f - m4.y) * -10000.f;
        float ma2 = (1.f - m4.z) * -10000.f, ma3 = (1.f - m4.w) * -10000.f;
        #pragma unroll
        for (int i = 0; i < 2; ++i) {
            int row = trow + 16*i;
            int qrow = q0 + row;
            float4 s4 = *(const float4*)&Sf[row*68 + c4*4];
            size_t doff = ((size_t)b*S_LEN + qrow)*S_LEN + kt*64 + c4*4;
            float4 d4 = *(const float4*)(dist + doff);
            float4 g4 = *(const float4*)(ang + doff);
            float4 s;
            s.x = s4.x*RSQRT_D + DW*d4.x + AW*g4.x + CB + ma0;
            s.y = s4.y*RSQRT_D + DW*d4.y + AW*g4.y + CB + ma1;
            s.z = s4.z*RSQRT_D + DW*d4.z + AW*g4.z + CB + ma2;
            s.w = s4.w*RSQRT_D + DW*d4.w + AW*g4.w + CB + ma3;
            *(float4*)(sc + ((size_t)bh*S_LEN + qrow)*S_LEN + kt*64 + c4*4) = s;

            float rmax = fmaxf(fmaxf(s.x, s.y), fmaxf(s.z, s.w));
            #pragma unroll
            for (int off = 1; off <= 8; off <<= 1) rmax = fmaxf(rmax, __shfl_xor(rmax, off));
            float mo = mL[row];
            float mn = fmaxf(mo, rmax);
            float es = __expf(s.x - mn) + __expf(s.y - mn) + __expf(s.z - mn) + __expf(s.w - mn);
            #pragma unroll
            for (int off = 1; off <= 8; off <<= 1) es += __shfl_xor(es, off);
            if (c4 == 0) {
                lL[row] = lL[row] * __expf(mo - mn) + es;
                mL[row] = mn;
            }
        }
        __syncthreads();
    }

    if (tid < 32) {
        mrow[(bh << 11) + q0 + tid] = mL[tid];
        lrow[(bh << 11) + q0 + tid] = lL[tid];
    }
}

// ---------------------------------------------------------------------------
// Pass 2 (softmax finish + PV): 32 q-rows/block, grid (64,16), block 256.
// Per kt: coalesced float4 read of raw scores -> p=exp(s-m)/l -> coalesced
// probs write -> bf16 -> swizzled LDS -> MFMA with Vt.
// ---------------------------------------------------------------------------
__global__ __launch_bounds__(256) void pv_mfma_kernel(
    const float* __restrict__ sc, const float* __restrict__ mrow,
    const float* __restrict__ lrow, const u16* __restrict__ vt,
    float* __restrict__ probs, u16* __restrict__ ctxb)
{
    const int bh = blockIdx.y, b = bh >> 3, h = bh & 7;
    const int q0 = blockIdx.x * 32;
    const int tid = threadIdx.x;
    const int lane = tid & 63, w = tid >> 6, lh = lane & 15, g = lane >> 4;
    const int wr = (w & 1) * 16;        // wave's q-row base
    const int wd = (w >> 1) * 48;       // wave's d-col base

    __shared__ __align__(16) u16 Ps[32*64];
    __shared__ __align__(16) u16 Vs[96*64];

    const int trow = tid >> 4, c4 = tid & 15;
    const float m0  = mrow[(bh << 11) + q0 + trow];
    const float m1  = mrow[(bh << 11) + q0 + trow + 16];
    const float il0 = 1.0f / lrow[(bh << 11) + q0 + trow];
    const float il1 = 1.0f / lrow[(bh << 11) + q0 + trow + 16];
    const float* srow0 = sc    + ((size_t)bh*S_LEN + q0 + trow)*S_LEN;
    const float* srow1 = srow0 + (size_t)16*S_LEN;
    float*       prow0 = probs + ((size_t)bh*S_LEN + q0 + trow)*S_LEN;
    float*       prow1 = prow0 + (size_t)16*S_LEN;

    f32x4 acc[3];
    #pragma unroll
    for (int j = 0; j < 3; ++j) acc[j] = (f32x4){0.f,0.f,0.f,0.f};

    for (int kt = 0; kt < 32; ++kt) {
        if (kt) __syncthreads();        // protect prev MFMA reads
        // finish softmax for this kt tile (2 rows x float4 per thread)
        {
            int coff = kt*64 + c4*4;
            int swzoff = ((trow*8 + ((c4 >> 1) ^ (trow & 7)))*8 + (c4 & 1)*4);
            float4 s4 = *(const float4*)(srow0 + coff);
            float4 p;
            p.x = __expf(s4.x - m0)*il0; p.y = __expf(s4.y - m0)*il0;
            p.z = __expf(s4.z - m0)*il0; p.w = __expf(s4.w - m0)*il0;
            *(float4*)(prow0 + coff) = p;
            U16x4 pk;
            pk.u[0] = f2bf(p.x); pk.u[1] = f2bf(p.y); pk.u[2] = f2bf(p.z); pk.u[3] = f2bf(p.w);
            *(uint2*)(Ps + swzoff) = pk.v2;

            s4 = *(const float4*)(srow1 + coff);
            p.x = __expf(s4.x - m1)*il1; p.y = __expf(s4.y - m1)*il1;
            p.z = __expf(s4.z - m1)*il1; p.w = __expf(s4.w - m1)*il1;
            *(float4*)(prow1 + coff) = p;
            pk.u[0] = f2bf(p.x); pk.u[1] = f2bf(p.y); pk.u[2] = f2bf(p.z); pk.u[3] = f2bf(p.w);
            *(uint2*)(Ps + (16*8*8) + swzoff) = pk.v2;   // rows 16..31
        }
        // stage Vt tile [96][64]
        #pragma unroll
        for (int i = 0; i < 3; ++i) {
            int idx = tid + 256*i;
            int vr = idx >> 3, c = idx & 7;
            float4 v4 = *(const float4*)(vt + ((size_t)bh*HD + vr)*S_LEN + kt*64 + c*8);
            *(float4*)(Vs + ((size_t)vr*8 + (c ^ (vr & 7)))*8) = v4;
        }
        __syncthreads();

        bf16x8 pa[2];
        #pragma unroll
        for (int kk = 0; kk < 2; ++kk) {
            int r = wr + lh;
            pa[kk] = *(const bf16x8*)(Ps + ((size_t)r*8 + ((kk*4+g) ^ (r & 7)))*8);
        }
        #pragma unroll
        for (int j = 0; j < 3; ++j)
            #pragma unroll
            for (int kk = 0; kk < 2; ++kk) {
                int vr = wd + j*16 + lh;
                bf16x8 vf = *(const bf16x8*)(Vs + ((size_t)vr*8 + ((kk*4+g) ^ (vr & 7)))*8);
                acc[j] = MFMA16(pa[kk], vf, acc[j]);
            }
    }

    #pragma unroll
    for (int j = 0; j < 3; ++j)
        #pragma unroll
        for (int r = 0; r < 4; ++r) {
            int qrow = q0 + wr + g*4 + r;
            ctxb[((size_t)(b*S_LEN + qrow))*EMB + h*HD + wd + j*16 + lh] = f2bf(acc[j][r]);
        }
}

// ---------------------------------------------------------------------------
// Output proj MFMA (unchanged from round 2)
// ---------------------------------------------------------------------------
__global__ __launch_bounds__(256) void out_mfma_kernel(
    const u16* __restrict__ ctxb, const u16* __restrict__ WoT,
    const float* __restrict__ bo, const float* __restrict__ hs,
    float* __restrict__ res)
{
    __shared__ __align__(16) u16 As[64*64];
    __shared__ __align__(16) u16 Bs[64*64];
    const int tid = threadIdx.x;
    const int w = tid >> 6, lane = tid & 63, lh = lane & 15, g = lane >> 4;
    const int wm = w >> 1, wn = w & 1;
    const int row0 = blockIdx.y * 64, col0 = blockIdx.x * 64;

    f32x4 acc[2][2];
    #pragma unroll
    for (int i = 0; i < 2; ++i)
        #pragma unroll
        for (int j = 0; j < 2; ++j) acc[i][j] = (f32x4){0.f,0.f,0.f,0.f};

    for (int k0 = 0; k0 < EMB; k0 += 64) {
        __syncthreads();
        #pragma unroll
        for (int i = 0; i < 2; ++i) {
            int idx = tid + 256*i;
            int r = idx >> 3, c = idx & 7;
            float4 a4 = *(const float4*)(ctxb + (size_t)(row0 + r)*EMB + k0 + c*8);
            *(float4*)(As + ((size_t)r*8 + (c ^ (r & 7)))*8) = a4;
            float4 b4 = *(const float4*)(WoT + (size_t)(col0 + r)*EMB + k0 + c*8);
            *(float4*)(Bs + ((size_t)r*8 + (c ^ (r & 7)))*8) = b4;
        }
        __syncthreads();
        bf16x8 af[2][2], bfr[2][2];
        #pragma unroll
        for (int mt = 0; mt < 2; ++mt)
            #pragma unroll
            for (int kk = 0; kk < 2; ++kk) {
                int r = wm*32 + mt*16 + lh;
                af[mt][kk] = *(const bf16x8*)(As + ((size_t)r*8 + ((kk*4+g) ^ (lh & 7)))*8);
            }
        #pragma unroll
        for (int nt = 0; nt < 2; ++nt)
            #pragma unroll
            for (int kk = 0; kk < 2; ++kk) {
                int r = wn*32 + nt*16 + lh;
                bfr[nt][kk] = *(const bf16x8*)(Bs + ((size_t)r*8 + ((kk*4+g) ^ (lh & 7)))*8);
            }
        #pragma unroll
        for (int mt = 0; mt < 2; ++mt)
            #pragma unroll
            for (int nt = 0; nt < 2; ++nt)
                #pragma unroll
                for (int kk = 0; kk < 2; ++kk)
                    acc[mt][nt] = MFMA16(af[mt][kk], bfr[nt][kk], acc[mt][nt]);
    }

    #pragma unroll
    for (int mt = 0; mt < 2; ++mt)
        #pragma unroll
        for (int nt = 0; nt < 2; ++nt)
            #pragma unroll
            for (int r = 0; r < 4; ++r) {
                int tt = row0 + wm*32 + mt*16 + g*4 + r;
                int o  = col0 + wn*32 + nt*16 + lh;
                res[(size_t)tt*EMB + o] = acc[mt][nt][r] + bo[o] + hs[(size_t)tt*EMB + o];
            }
}

// ---------------------------------------------------------------------------
// LayerNorm in place over last dim 768. grid NTOK, block 256.
// ---------------------------------------------------------------------------
__device__ __forceinline__ float block_sum256(float v, float* red) {
    #pragma unroll
    for (int off = 32; off > 0; off >>= 1) v += __shfl_down(v, off);
    int lane = threadIdx.x & 63, w = threadIdx.x >> 6;
    __syncthreads();
    if (lane == 0) red[w] = v;
    __syncthreads();
    return red[0] + red[1] + red[2] + red[3];
}

__global__ __launch_bounds__(256) void ln_kernel(
    float* __restrict__ res, const float* __restrict__ gamma, const float* __restrict__ beta)
{
    const int t = blockIdx.x;
    float* row = res + (size_t)t * EMB;
    const int tid = threadIdx.x;
    __shared__ float red[4];

    float x0 = row[tid], x1 = row[tid + 256], x2 = row[tid + 512];
    float s = block_sum256(x0 + x1 + x2, red);
    float mu = s * (1.0f / (float)EMB);
    float d0 = x0 - mu, d1 = x1 - mu, d2 = x2 - mu;
    float sq = block_sum256(d0*d0 + d1*d1 + d2*d2, red);
    float var = sq * (1.0f / (float)EMB);
    float scale = rsqrtf(var + 1e-5f);

    row[tid]       = d0 * scale * gamma[tid]       + beta[tid];
    row[tid + 256] = d1 * scale * gamma[tid + 256] + beta[tid + 256];
    row[tid + 512] = d2 * scale * gamma[tid + 512] + beta[tid + 512];
}

// ---------------------------------------------------------------------------
extern "C" void kernel_launch(void* const* d_in, const int* in_sizes, int n_in,
                              void* d_out, int out_size, void* d_ws, size_t ws_size,
                              hipStream_t stream)
{
    (void)in_sizes; (void)n_in; (void)out_size; (void)ws_size;

    const float* hs   = (const float*)d_in[0];
    const float* dist = (const float*)d_in[1];
    const float* ang  = (const float*)d_in[2];
    const float* mask = (const float*)d_in[3];
    const float* Wq = (const float*)d_in[4];  const float* bq = (const float*)d_in[5];
    const float* Wk = (const float*)d_in[6];  const float* bk = (const float*)d_in[7];
    const float* Wv = (const float*)d_in[8];  const float* bv = (const float*)d_in[9];
    const float* dw = (const float*)d_in[10]; const float* db = (const float*)d_in[11];
    const float* aw = (const float*)d_in[12]; const float* ab = (const float*)d_in[13];
    const float* Wo = (const float*)d_in[14]; const float* bo = (const float*)d_in[15];
    const float* gamma = (const float*)d_in[16]; const float* beta = (const float*)d_in[17];

    float* out   = (float*)d_out;                      // [B,S,E]
    float* probs = out + (size_t)NTOK * EMB;           // [B,H,S,S]

    u16* hsb = (u16*)d_ws;
    u16* WqT = hsb + (size_t)NTOK*EMB;
    u16* WkT = WqT + (size_t)EMB*EMB;
    u16* WvT = WkT + (size_t)EMB*EMB;
    u16* WoT = WvT + (size_t)EMB*EMB;
    u16* qb  = WoT + (size_t)EMB*EMB;
    u16* kb  = qb + (size_t)NTOK*EMB;
    u16* vb  = kb + (size_t)NTOK*EMB;
    u16* vtb = vb + (size_t)NTOK*EMB;
    u16* ctxb = qb;                                    // reuse q region after scores
    float* mrow = (float*)(vtb + (size_t)NTOK*EMB);
    float* lrow = mrow + (size_t)BATCH*NH*S_LEN;

    cvt_bf16_kernel<<<dim3(NTOK*EMB/4/256), dim3(256), 0, stream>>>(hs, hsb, NTOK*EMB/4);
    transcvt_kernel<<<dim3(12,12), dim3(256), 0, stream>>>(Wq, WqT);
    transcvt_kernel<<<dim3(12,12), dim3(256), 0, stream>>>(Wk, WkT);
    transcvt_kernel<<<dim3(12,12), dim3(256), 0, stream>>>(Wv, WvT);
    transcvt_kernel<<<dim3(12,12), dim3(256), 0, stream>>>(Wo, WoT);

    qkv_mfma_kernel<<<dim3(EMB/64, NTOK/64, 3), dim3(256), 0, stream>>>(
        hsb, WqT, bq, WkT, bk, WvT, bv, qb, kb, vb);

    vtrans_kernel<<<dim3(S_LEN/64, BATCH*NH), dim3(256), 0, stream>>>(vb, vtb);

    scores_mfma_kernel<<<dim3(S_LEN/32, BATCH*NH), dim3(256), 0, stream>>>(
        qb, kb, dist, ang, mask, dw, db, aw, ab, probs, mrow, lrow);

    pv_mfma_kernel<<<dim3(S_LEN/32, BATCH*NH), dim3(256), 0, stream>>>(
        probs, mrow, lrow, vtb, probs, ctxb);

    out_mfma_kernel<<<dim3(EMB/64, NTOK/64), dim3(256), 0, stream>>>(
        ctxb, WoT, bo, hs, out);

    ln_kernel<<<dim3(NTOK), dim3(256), 0, stream>>>(out, gamma, beta);
}

// Round 4
// 308.300 us; speedup vs baseline: 2.4261x; 1.2067x over previous
//
#include <hip/hip_runtime.h>
#include <math.h>

#define S_LEN 2048
#define BATCH 2
#define EMB 768
#define NH 8
#define HD 96
#define NTOK (BATCH*S_LEN)
#define RSQRT_D 0.10206207261596575f   // 1/sqrt(96)

typedef unsigned short u16;
typedef __attribute__((ext_vector_type(8))) short bf16x8;
typedef __attribute__((ext_vector_type(4))) float f32x4;

#define MFMA16(a,b,c) __builtin_amdgcn_mfma_f32_16x16x32_bf16(a,b,c,0,0,0)

__device__ __forceinline__ u16 f2bf(float f){
    unsigned u = __float_as_uint(f);
    return (u16)((u + 0x7fffu + ((u>>16)&1u)) >> 16);
}
__device__ __forceinline__ float bf2f(unsigned u){
    return __uint_as_float(u << 16);
}

union U16x8 { u16 u[8]; float4 f4; };
union U16x4 { u16 u[4]; uint2 v2; };

// ---------------------------------------------------------------------------
// f32 -> bf16 elementwise convert (vectorized x4)
// ---------------------------------------------------------------------------
__global__ __launch_bounds__(256) void cvt_bf16_kernel(
    const float* __restrict__ src, u16* __restrict__ dst, int n4)
{
    int i = blockIdx.x * 256 + threadIdx.x;
    if (i < n4) {
        float4 v = ((const float4*)src)[i];
        U16x4 o;
        o.u[0] = f2bf(v.x); o.u[1] = f2bf(v.y); o.u[2] = f2bf(v.z); o.u[3] = f2bf(v.w);
        *(uint2*)(dst + (size_t)i*4) = o.v2;
    }
}

// ---------------------------------------------------------------------------
// W[768][768] f32 -> Wt[n][k] bf16 (transpose + convert). grid (12,12), 256thr
// ---------------------------------------------------------------------------
__global__ __launch_bounds__(256) void transcvt_kernel(
    const float* __restrict__ W, u16* __restrict__ Wt)
{
    __shared__ float T[64][65];
    const int t = threadIdx.x;
    const int k0 = blockIdx.y * 64, n0 = blockIdx.x * 64;
    #pragma unroll
    for (int i = 0; i < 4; ++i) {
        int idx = t + 256*i;
        int r = idx >> 4, c4 = idx & 15;
        float4 v = *(const float4*)(W + (size_t)(k0 + r)*EMB + n0 + c4*4);
        T[r][c4*4+0] = v.x; T[r][c4*4+1] = v.y; T[r][c4*4+2] = v.z; T[r][c4*4+3] = v.w;
    }
    __syncthreads();
    #pragma unroll
    for (int i = 0; i < 2; ++i) {
        int idx = t + 256*i;
        int n = idx >> 3, c = idx & 7;
        U16x8 o;
        #pragma unroll
        for (int e = 0; e < 8; ++e) o.u[e] = f2bf(T[c*8+e][n]);
        *(float4*)(Wt + (size_t)(n0 + n)*EMB + k0 + c*8) = o.f4;
    }
}

// ---------------------------------------------------------------------------
// QKV projection MFMA (unchanged)
// ---------------------------------------------------------------------------
__global__ __launch_bounds__(256) void qkv_mfma_kernel(
    const u16* __restrict__ hsb,
    const u16* __restrict__ WqT, const float* __restrict__ bq,
    const u16* __restrict__ WkT, const float* __restrict__ bk,
    const u16* __restrict__ WvT, const float* __restrict__ bv,
    u16* __restrict__ qo, u16* __restrict__ ko, u16* __restrict__ vo)
{
    const u16* Wt; const float* bias; u16* out;
    if (blockIdx.z == 0)      { Wt = WqT; bias = bq; out = qo; }
    else if (blockIdx.z == 1) { Wt = WkT; bias = bk; out = ko; }
    else                      { Wt = WvT; bias = bv; out = vo; }

    __shared__ __align__(16) u16 As[64*64];
    __shared__ __align__(16) u16 Bs[64*64];
    const int tid = threadIdx.x;
    const int w = tid >> 6, lane = tid & 63, lh = lane & 15, g = lane >> 4;
    const int wm = w >> 1, wn = w & 1;
    const int row0 = blockIdx.y * 64, col0 = blockIdx.x * 64;

    f32x4 acc[2][2];
    #pragma unroll
    for (int i = 0; i < 2; ++i)
        #pragma unroll
        for (int j = 0; j < 2; ++j) acc[i][j] = (f32x4){0.f,0.f,0.f,0.f};

    for (int k0 = 0; k0 < EMB; k0 += 64) {
        __syncthreads();
        #pragma unroll
        for (int i = 0; i < 2; ++i) {
            int idx = tid + 256*i;
            int r = idx >> 3, c = idx & 7;
            float4 a4 = *(const float4*)(hsb + (size_t)(row0 + r)*EMB + k0 + c*8);
            *(float4*)(As + ((size_t)r*8 + (c ^ (r & 7)))*8) = a4;
            float4 b4 = *(const float4*)(Wt + (size_t)(col0 + r)*EMB + k0 + c*8);
            *(float4*)(Bs + ((size_t)r*8 + (c ^ (r & 7)))*8) = b4;
        }
        __syncthreads();
        bf16x8 af[2][2], bfr[2][2];
        #pragma unroll
        for (int mt = 0; mt < 2; ++mt)
            #pragma unroll
            for (int kk = 0; kk < 2; ++kk) {
                int r = wm*32 + mt*16 + lh;
                af[mt][kk] = *(const bf16x8*)(As + ((size_t)r*8 + ((kk*4+g) ^ (lh & 7)))*8);
            }
        #pragma unroll
        for (int nt = 0; nt < 2; ++nt)
            #pragma unroll
            for (int kk = 0; kk < 2; ++kk) {
                int r = wn*32 + nt*16 + lh;
                bfr[nt][kk] = *(const bf16x8*)(Bs + ((size_t)r*8 + ((kk*4+g) ^ (lh & 7)))*8);
            }
        #pragma unroll
        for (int mt = 0; mt < 2; ++mt)
            #pragma unroll
            for (int nt = 0; nt < 2; ++nt)
                #pragma unroll
                for (int kk = 0; kk < 2; ++kk)
                    acc[mt][nt] = MFMA16(af[mt][kk], bfr[nt][kk], acc[mt][nt]);
    }

    #pragma unroll
    for (int mt = 0; mt < 2; ++mt)
        #pragma unroll
        for (int nt = 0; nt < 2; ++nt)
            #pragma unroll
            for (int r = 0; r < 4; ++r) {
                int tt = row0 + wm*32 + mt*16 + g*4 + r;
                int o  = col0 + wn*32 + nt*16 + lh;
                float val = acc[mt][nt][r] + bias[o];
                int b = tt >> 11, s = tt & (S_LEN - 1);
                int h = o / HD, d = o - h*HD;
                out[((size_t)(b*NH + h)*S_LEN + s)*HD + d] = f2bf(val);
            }
}

// ---------------------------------------------------------------------------
// V transpose: vb[B,H,S,D] bf16 -> vt[B,H,D,S] bf16 (unchanged)
// ---------------------------------------------------------------------------
__global__ __launch_bounds__(256) void vtrans_kernel(
    const u16* __restrict__ vb, u16* __restrict__ vt)
{
    const int bh = blockIdx.y;
    const int s0 = blockIdx.x * 64;
    __shared__ __align__(16) u16 T[64*96];
    const int t = threadIdx.x;
    #pragma unroll
    for (int i = 0; i < 3; ++i) {
        int idx = t + 256*i;
        int s = idx / 12, c = idx % 12;
        float4 v = *(const float4*)(vb + ((size_t)bh*S_LEN + s0 + s)*HD + c*8);
        *(float4*)(T + ((size_t)s*12 + c)*8) = v;
    }
    __syncthreads();
    #pragma unroll
    for (int i = 0; i < 3; ++i) {
        int idx = t + 256*i;
        int d = idx >> 3, c = idx & 7;
        U16x8 o;
        #pragma unroll
        for (int e = 0; e < 8; ++e) o.u[e] = T[(size_t)(c*8+e)*HD + d];
        *(float4*)(vt + ((size_t)bh*HD + d)*S_LEN + s0 + c*8) = o.f4;
    }
}

// ---------------------------------------------------------------------------
// Pass 1 (scores): 32 q-rows/block, grid (64,16), block 256.
// Per kt: prefetch dist/ang -> stage K -> MFMA -> acc->LDS -> epilogue:
// s = acc*scl + bias + mask; online m,l; write u=exp(s-m_run) bf16 + alpha.
// NO raw-score f32 write.
// ---------------------------------------------------------------------------
__global__ __launch_bounds__(256) void scores_mfma_kernel(
    const u16* __restrict__ qbf, const u16* __restrict__ kbf,
    const float* __restrict__ dist, const float* __restrict__ ang,
    const float* __restrict__ mask,
    const float* __restrict__ pdw, const float* __restrict__ pdb,
    const float* __restrict__ paw, const float* __restrict__ pab,
    u16* __restrict__ ubuf, float* __restrict__ alpha,
    float* __restrict__ mrow, float* __restrict__ lrow)
{
    const int bh = blockIdx.y, b = bh >> 3;
    const int q0 = blockIdx.x * 32;
    const int tid = threadIdx.x;
    const int lane = tid & 63, w = tid >> 6, lh = lane & 15, g = lane >> 4;
    const int wr = (w & 1) * 16;
    const int wc = (w >> 1) * 32;

    __shared__ __align__(16) u16 Qs[32*96];
    __shared__ __align__(16) u16 Ks[64*96];
    __shared__ __align__(16) float Sf[32*68];
    __shared__ float mL[32], lL[32];

    #pragma unroll
    for (int i = 0; i < 2; ++i) {
        int idx = tid + 256*i;
        if (idx < 384) {
            int r = idx / 12, c = idx % 12;
            float4 v = *(const float4*)(qbf + ((size_t)bh*S_LEN + q0 + r)*HD + c*8);
            *(float4*)(Qs + ((size_t)r*12 + (c ^ ((r >> 1) & 3)))*8) = v;
        }
    }
    if (tid < 32) { mL[tid] = -1e30f; lL[tid] = 0.f; }
    __syncthreads();

    bf16x8 qf[3];
    #pragma unroll
    for (int kk = 0; kk < 3; ++kk) {
        int r = wr + lh;
        qf[kk] = *(const bf16x8*)(Qs + ((size_t)r*12 + ((kk*4+g) ^ ((r >> 1) & 3)))*8);
    }

    const float DW = *pdw, AW = *paw, CB = *pdb + *pab;
    const int trow = tid >> 4;
    const int c4   = tid & 15;
    const size_t drow0 = ((size_t)b*S_LEN + q0 + trow)*S_LEN;
    const size_t drow1 = drow0 + (size_t)16*S_LEN;

    for (int kt = 0; kt < 32; ++kt) {
        // prefetch dist/ang for this kt (consumed after MFMA)
        int coff = kt*64 + c4*4;
        float4 d40 = *(const float4*)(dist + drow0 + coff);
        float4 g40 = *(const float4*)(ang  + drow0 + coff);
        float4 d41 = *(const float4*)(dist + drow1 + coff);
        float4 g41 = *(const float4*)(ang  + drow1 + coff);
        float4 m4  = *(const float4*)(mask + b*S_LEN + coff);

        // stage K tile (64 rows x 12 chunks)
        #pragma unroll
        for (int i = 0; i < 3; ++i) {
            int idx = tid + 256*i;
            int r = idx / 12, c = idx % 12;
            float4 v = *(const float4*)(kbf + ((size_t)bh*S_LEN + kt*64 + r)*HD + c*8);
            *(float4*)(Ks + ((size_t)r*12 + (c ^ ((r >> 1) & 3)))*8) = v;
        }
        __syncthreads();

        f32x4 acc[2];
        #pragma unroll
        for (int ct = 0; ct < 2; ++ct) acc[ct] = (f32x4){0.f,0.f,0.f,0.f};
        #pragma unroll
        for (int ct = 0; ct < 2; ++ct)
            #pragma unroll
            for (int kk = 0; kk < 3; ++kk) {
                int kr = wc + ct*16 + lh;
                bf16x8 kf = *(const bf16x8*)(Ks + ((size_t)kr*12 + ((kk*4+g) ^ ((kr >> 1) & 3)))*8);
                acc[ct] = MFMA16(qf[kk], kf, acc[ct]);
            }
        #pragma unroll
        for (int ct = 0; ct < 2; ++ct)
            #pragma unroll
            for (int r = 0; r < 4; ++r)
                Sf[(wr + g*4 + r)*68 + wc + ct*16 + lh] = acc[ct][r];
        __syncthreads();

        float ma0 = (1.f - m4.x) * -10000.f, ma1 = (1.f - m4.y) * -10000.f;
        float ma2 = (1.f - m4.z) * -10000.f, ma3 = (1.f - m4.w) * -10000.f;
        #pragma unroll
        for (int i = 0; i < 2; ++i) {
            int row = trow + 16*i;
            int qrow = q0 + row;
            float4 s4 = *(const float4*)&Sf[row*68 + c4*4];
            float4 dd = i ? d41 : d40;
            float4 gg = i ? g41 : g40;
            float sx = s4.x*RSQRT_D + DW*dd.x + AW*gg.x + CB + ma0;
            float sy = s4.y*RSQRT_D + DW*dd.y + AW*gg.y + CB + ma1;
            float sz = s4.z*RSQRT_D + DW*dd.z + AW*gg.z + CB + ma2;
            float sw = s4.w*RSQRT_D + DW*dd.w + AW*gg.w + CB + ma3;

            float rmax = fmaxf(fmaxf(sx, sy), fmaxf(sz, sw));
            #pragma unroll
            for (int off = 1; off <= 8; off <<= 1) rmax = fmaxf(rmax, __shfl_xor(rmax, off));
            float mo = mL[row];
            float mn = fmaxf(mo, rmax);
            float e0 = __expf(sx - mn), e1 = __expf(sy - mn);
            float e2 = __expf(sz - mn), e3 = __expf(sw - mn);
            float es = (e0 + e1) + (e2 + e3);
            #pragma unroll
            for (int off = 1; off <= 8; off <<= 1) es += __shfl_xor(es, off);

            U16x4 uk;
            uk.u[0] = f2bf(e0); uk.u[1] = f2bf(e1); uk.u[2] = f2bf(e2); uk.u[3] = f2bf(e3);
            *(uint2*)(ubuf + ((size_t)bh*S_LEN + qrow)*S_LEN + coff) = uk.v2;

            if (c4 == 0) {
                lL[row] = lL[row] * __expf(mo - mn) + es;
                mL[row] = mn;
                alpha[((size_t)bh*32 + kt)*S_LEN + qrow] = mn;
            }
        }
        __syncthreads();
    }

    if (tid < 32) {
        mrow[(bh << 11) + q0 + tid] = mL[tid];
        lrow[(bh << 11) + q0 + tid] = lL[tid];
    }
}

// ---------------------------------------------------------------------------
// Pass 2 (PV + probs): p = u * exp(alpha - m_fin)/l. One expf per row per kt.
// grid (64,16), block 256.
// ---------------------------------------------------------------------------
__global__ __launch_bounds__(256) void pv_mfma_kernel(
    const u16* __restrict__ ubuf, const float* __restrict__ alpha,
    const float* __restrict__ mrow, const float* __restrict__ lrow,
    const u16* __restrict__ vt,
    float* __restrict__ probs, u16* __restrict__ ctxb)
{
    const int bh = blockIdx.y, b = bh >> 3, h = bh & 7;
    const int q0 = blockIdx.x * 32;
    const int tid = threadIdx.x;
    const int lane = tid & 63, w = tid >> 6, lh = lane & 15, g = lane >> 4;
    const int wr = (w & 1) * 16;        // wave's q-row base
    const int wd = (w >> 1) * 48;       // wave's d-col base

    __shared__ __align__(16) u16 Ps[32*64];
    __shared__ __align__(16) u16 Vs[96*64];

    const int trow = tid >> 4, c4 = tid & 15;
    const float m0  = mrow[(bh << 11) + q0 + trow];
    const float m1  = mrow[(bh << 11) + q0 + trow + 16];
    const float il0 = 1.0f / lrow[(bh << 11) + q0 + trow];
    const float il1 = 1.0f / lrow[(bh << 11) + q0 + trow + 16];
    const u16* urow0 = ubuf + ((size_t)bh*S_LEN + q0 + trow)*S_LEN;
    const u16* urow1 = urow0 + (size_t)16*S_LEN;
    float*     prow0 = probs + ((size_t)bh*S_LEN + q0 + trow)*S_LEN;
    float*     prow1 = prow0 + (size_t)16*S_LEN;

    f32x4 acc[3];
    #pragma unroll
    for (int j = 0; j < 3; ++j) acc[j] = (f32x4){0.f,0.f,0.f,0.f};

    for (int kt = 0; kt < 32; ++kt) {
        if (kt) __syncthreads();
        int coff = kt*64 + c4*4;
        // issue u + alpha loads early
        uint2 ua = *(const uint2*)(urow0 + coff);
        uint2 ub = *(const uint2*)(urow1 + coff);
        float a0 = alpha[((size_t)bh*32 + kt)*S_LEN + q0 + trow];
        float a1 = alpha[((size_t)bh*32 + kt)*S_LEN + q0 + trow + 16];
        // stage Vt tile [96][64] (independent loads overlap u latency)
        #pragma unroll
        for (int i = 0; i < 3; ++i) {
            int idx = tid + 256*i;
            int vr = idx >> 3, c = idx & 7;
            float4 v4 = *(const float4*)(vt + ((size_t)bh*HD + vr)*S_LEN + kt*64 + c*8);
            *(float4*)(Vs + ((size_t)vr*8 + (c ^ (vr & 7)))*8) = v4;
        }
        // finish probs for this kt tile
        float sc0 = __expf(a0 - m0) * il0;
        float sc1 = __expf(a1 - m1) * il1;
        int swzoff = ((trow*8 + ((c4 >> 1) ^ (trow & 7)))*8 + (c4 & 1)*4);
        {
            float4 p;
            p.x = bf2f(ua.x & 0xffffu)*sc0; p.y = bf2f(ua.x >> 16)*sc0;
            p.z = bf2f(ua.y & 0xffffu)*sc0; p.w = bf2f(ua.y >> 16)*sc0;
            *(float4*)(prow0 + coff) = p;
            U16x4 pk;
            pk.u[0] = f2bf(p.x); pk.u[1] = f2bf(p.y); pk.u[2] = f2bf(p.z); pk.u[3] = f2bf(p.w);
            *(uint2*)(Ps + swzoff) = pk.v2;

            p.x = bf2f(ub.x & 0xffffu)*sc1; p.y = bf2f(ub.x >> 16)*sc1;
            p.z = bf2f(ub.y & 0xffffu)*sc1; p.w = bf2f(ub.y >> 16)*sc1;
            *(float4*)(prow1 + coff) = p;
            pk.u[0] = f2bf(p.x); pk.u[1] = f2bf(p.y); pk.u[2] = f2bf(p.z); pk.u[3] = f2bf(p.w);
            *(uint2*)(Ps + (16*8*8) + swzoff) = pk.v2;
        }
        __syncthreads();

        bf16x8 pa[2];
        #pragma unroll
        for (int kk = 0; kk < 2; ++kk) {
            int r = wr + lh;
            pa[kk] = *(const bf16x8*)(Ps + ((size_t)r*8 + ((kk*4+g) ^ (r & 7)))*8);
        }
        #pragma unroll
        for (int j = 0; j < 3; ++j)
            #pragma unroll
            for (int kk = 0; kk < 2; ++kk) {
                int vr = wd + j*16 + lh;
                bf16x8 vf = *(const bf16x8*)(Vs + ((size_t)vr*8 + ((kk*4+g) ^ (vr & 7)))*8);
                acc[j] = MFMA16(pa[kk], vf, acc[j]);
            }
    }

    #pragma unroll
    for (int j = 0; j < 3; ++j)
        #pragma unroll
        for (int r = 0; r < 4; ++r) {
            int qrow = q0 + wr + g*4 + r;
            ctxb[((size_t)(b*S_LEN + qrow))*EMB + h*HD + wd + j*16 + lh] = f2bf(acc[j][r]);
        }
}

// ---------------------------------------------------------------------------
// Output proj MFMA (unchanged)
// ---------------------------------------------------------------------------
__global__ __launch_bounds__(256) void out_mfma_kernel(
    const u16* __restrict__ ctxb, const u16* __restrict__ WoT,
    const float* __restrict__ bo, const float* __restrict__ hs,
    float* __restrict__ res)
{
    __shared__ __align__(16) u16 As[64*64];
    __shared__ __align__(16) u16 Bs[64*64];
    const int tid = threadIdx.x;
    const int w = tid >> 6, lane = tid & 63, lh = lane & 15, g = lane >> 4;
    const int wm = w >> 1, wn = w & 1;
    const int row0 = blockIdx.y * 64, col0 = blockIdx.x * 64;

    f32x4 acc[2][2];
    #pragma unroll
    for (int i = 0; i < 2; ++i)
        #pragma unroll
        for (int j = 0; j < 2; ++j) acc[i][j] = (f32x4){0.f,0.f,0.f,0.f};

    for (int k0 = 0; k0 < EMB; k0 += 64) {
        __syncthreads();
        #pragma unroll
        for (int i = 0; i < 2; ++i) {
            int idx = tid + 256*i;
            int r = idx >> 3, c = idx & 7;
            float4 a4 = *(const float4*)(ctxb + (size_t)(row0 + r)*EMB + k0 + c*8);
            *(float4*)(As + ((size_t)r*8 + (c ^ (r & 7)))*8) = a4;
            float4 b4 = *(const float4*)(WoT + (size_t)(col0 + r)*EMB + k0 + c*8);
            *(float4*)(Bs + ((size_t)r*8 + (c ^ (r & 7)))*8) = b4;
        }
        __syncthreads();
        bf16x8 af[2][2], bfr[2][2];
        #pragma unroll
        for (int mt = 0; mt < 2; ++mt)
            #pragma unroll
            for (int kk = 0; kk < 2; ++kk) {
                int r = wm*32 + mt*16 + lh;
                af[mt][kk] = *(const bf16x8*)(As + ((size_t)r*8 + ((kk*4+g) ^ (lh & 7)))*8);
            }
        #pragma unroll
        for (int nt = 0; nt < 2; ++nt)
            #pragma unroll
            for (int kk = 0; kk < 2; ++kk) {
                int r = wn*32 + nt*16 + lh;
                bfr[nt][kk] = *(const bf16x8*)(Bs + ((size_t)r*8 + ((kk*4+g) ^ (lh & 7)))*8);
            }
        #pragma unroll
        for (int mt = 0; mt < 2; ++mt)
            #pragma unroll
            for (int nt = 0; nt < 2; ++nt)
                #pragma unroll
                for (int kk = 0; kk < 2; ++kk)
                    acc[mt][nt] = MFMA16(af[mt][kk], bfr[nt][kk], acc[mt][nt]);
    }

    #pragma unroll
    for (int mt = 0; mt < 2; ++mt)
        #pragma unroll
        for (int nt = 0; nt < 2; ++nt)
            #pragma unroll
            for (int r = 0; r < 4; ++r) {
                int tt = row0 + wm*32 + mt*16 + g*4 + r;
                int o  = col0 + wn*32 + nt*16 + lh;
                res[(size_t)tt*EMB + o] = acc[mt][nt][r] + bo[o] + hs[(size_t)tt*EMB + o];
            }
}

// ---------------------------------------------------------------------------
// LayerNorm in place over last dim 768. grid NTOK, block 256.
// ---------------------------------------------------------------------------
__device__ __forceinline__ float block_sum256(float v, float* red) {
    #pragma unroll
    for (int off = 32; off > 0; off >>= 1) v += __shfl_down(v, off);
    int lane = threadIdx.x & 63, w = threadIdx.x >> 6;
    __syncthreads();
    if (lane == 0) red[w] = v;
    __syncthreads();
    return red[0] + red[1] + red[2] + red[3];
}

__global__ __launch_bounds__(256) void ln_kernel(
    float* __restrict__ res, const float* __restrict__ gamma, const float* __restrict__ beta)
{
    const int t = blockIdx.x;
    float* row = res + (size_t)t * EMB;
    const int tid = threadIdx.x;
    __shared__ float red[4];

    float x0 = row[tid], x1 = row[tid + 256], x2 = row[tid + 512];
    float s = block_sum256(x0 + x1 + x2, red);
    float mu = s * (1.0f / (float)EMB);
    float d0 = x0 - mu, d1 = x1 - mu, d2 = x2 - mu;
    float sq = block_sum256(d0*d0 + d1*d1 + d2*d2, red);
    float var = sq * (1.0f / (float)EMB);
    float scale = rsqrtf(var + 1e-5f);

    row[tid]       = d0 * scale * gamma[tid]       + beta[tid];
    row[tid + 256] = d1 * scale * gamma[tid + 256] + beta[tid + 256];
    row[tid + 512] = d2 * scale * gamma[tid + 512] + beta[tid + 512];
}

// ---------------------------------------------------------------------------
extern "C" void kernel_launch(void* const* d_in, const int* in_sizes, int n_in,
                              void* d_out, int out_size, void* d_ws, size_t ws_size,
                              hipStream_t stream)
{
    (void)in_sizes; (void)n_in; (void)out_size; (void)ws_size;

    const float* hs   = (const float*)d_in[0];
    const float* dist = (const float*)d_in[1];
    const float* ang  = (const float*)d_in[2];
    const float* mask = (const float*)d_in[3];
    const float* Wq = (const float*)d_in[4];  const float* bq = (const float*)d_in[5];
    const float* Wk = (const float*)d_in[6];  const float* bk = (const float*)d_in[7];
    const float* Wv = (const float*)d_in[8];  const float* bv = (const float*)d_in[9];
    const float* dw = (const float*)d_in[10]; const float* db = (const float*)d_in[11];
    const float* aw = (const float*)d_in[12]; const float* ab = (const float*)d_in[13];
    const float* Wo = (const float*)d_in[14]; const float* bo = (const float*)d_in[15];
    const float* gamma = (const float*)d_in[16]; const float* beta = (const float*)d_in[17];

    float* out   = (float*)d_out;                      // [B,S,E]
    float* probs = out + (size_t)NTOK * EMB;           // [B,H,S,S]

    u16* hsb = (u16*)d_ws;
    u16* WqT = hsb + (size_t)NTOK*EMB;
    u16* WkT = WqT + (size_t)EMB*EMB;
    u16* WvT = WkT + (size_t)EMB*EMB;
    u16* WoT = WvT + (size_t)EMB*EMB;
    u16* qb  = WoT + (size_t)EMB*EMB;
    u16* kb  = qb + (size_t)NTOK*EMB;
    u16* vb  = kb + (size_t)NTOK*EMB;
    u16* vtb = vb + (size_t)NTOK*EMB;
    u16* ctxb = qb;                                    // reuse q region after scores
    float* mrow  = (float*)(vtb + (size_t)NTOK*EMB);
    float* lrow  = mrow + (size_t)BATCH*NH*S_LEN;
    float* alpha = lrow + (size_t)BATCH*NH*S_LEN;      // [bh][32 kt][2048] = 4 MB
    u16*   ubuf  = (u16*)(alpha + (size_t)BATCH*NH*32*S_LEN);  // [bh][2048][2048] bf16 = 134 MB

    cvt_bf16_kernel<<<dim3(NTOK*EMB/4/256), dim3(256), 0, stream>>>(hs, hsb, NTOK*EMB/4);
    transcvt_kernel<<<dim3(12,12), dim3(256), 0, stream>>>(Wq, WqT);
    transcvt_kernel<<<dim3(12,12), dim3(256), 0, stream>>>(Wk, WkT);
    transcvt_kernel<<<dim3(12,12), dim3(256), 0, stream>>>(Wv, WvT);
    transcvt_kernel<<<dim3(12,12), dim3(256), 0, stream>>>(Wo, WoT);

    qkv_mfma_kernel<<<dim3(EMB/64, NTOK/64, 3), dim3(256), 0, stream>>>(
        hsb, WqT, bq, WkT, bk, WvT, bv, qb, kb, vb);

    vtrans_kernel<<<dim3(S_LEN/64, BATCH*NH), dim3(256), 0, stream>>>(vb, vtb);

    scores_mfma_kernel<<<dim3(S_LEN/32, BATCH*NH), dim3(256), 0, stream>>>(
        qb, kb, dist, ang, mask, dw, db, aw, ab, ubuf, alpha, mrow, lrow);

    pv_mfma_kernel<<<dim3(S_LEN/32, BATCH*NH), dim3(256), 0, stream>>>(
        ubuf, alpha, mrow, lrow, vtb, probs, ctxb);

    out_mfma_kernel<<<dim3(EMB/64, NTOK/64), dim3(256), 0, stream>>>(
        ctxb, WoT, bo, hs, out);

    ln_kernel<<<dim3(NTOK), dim3(256), 0, stream>>>(out, gamma, beta);
}